// Round 2
// baseline (8355.058 us; speedup 1.0000x reference)
//
#include <hip/hip_runtime.h>
#include <stdint.h>
#include <math.h>

typedef __attribute__((ext_vector_type(8))) short bf16x8;
typedef __attribute__((ext_vector_type(4))) float f32x4;
typedef unsigned short u16;

__device__ __forceinline__ short f2bf(float f){
  union { float f; uint32_t u; } v; v.f = f;
  uint32_t r = v.u + 0x7FFFu + ((v.u >> 16) & 1u);
  return (short)(r >> 16);
}
// bool inputs may arrive as uint8 (numpy bool) or int32; runtime-detected flag selects.
__device__ __forceinline__ bool getb(const void* p, int i, int flag){
  if (flag) return ((const unsigned char*)p)[i] != 0;
  return ((const int*)p)[i] != 0;
}
__device__ __forceinline__ bf16x8 ldx8(const float* xp){
  f32x4 x0 = *(const f32x4*)xp;
  f32x4 x1 = *(const f32x4*)(xp + 4);
  bf16x8 a;
  a[0]=f2bf(x0[0]); a[1]=f2bf(x0[1]); a[2]=f2bf(x0[2]); a[3]=f2bf(x0[3]);
  a[4]=f2bf(x1[0]); a[5]=f2bf(x1[1]); a[6]=f2bf(x1[2]); a[7]=f2bf(x1[3]);
  return a;
}

__global__ void detect_bool_k(const void* pad, int* flag){
  // if bools are int32 {0,1}, bytes at i%4!=0 are all zero; if uint8 (~80% ones), some are 1.
  const unsigned char* b = (const unsigned char*)pad;
  int f = 0;
  for (int i = 1; i < 64; ++i) if (i & 3) f |= (b[i] != 0) ? 1 : 0;
  *flag = f;
}

__global__ void transpose_k(const float* __restrict__ src, u16* __restrict__ dst, int R, int C){
  // src f32 [mats][R][C] -> dst bf16 [mats][C][R]; grid*256 == mats*R*C exactly
  long idx = (long)blockIdx.x * blockDim.x + threadIdx.x;
  int r = (int)(idx % R);
  long t = idx / R;
  int c = (int)(t % C);
  int m = (int)(t / C);
  dst[idx] = (u16)f2bf(src[((long)m * R + r) * C + c]);
}

__global__ void pos_init_k(const int* __restrict__ pos, float* __restrict__ reprs){
  int n = blockIdx.x, d = threadIdx.x;
  double p = (double)pos[n];
  int i = (d < 128) ? d : d - 128;
  double ang = p / pow(500.0, (2.0 * (double)i) / 256.0);
  reprs[n * 256 + d] = (d < 128) ? (float)sin(ang) : (float)cos(ang);
}

__global__ void update_k(const int* __restrict__ sortv, const float* __restrict__ encCLS,
                         float* __restrict__ reprs, int rank){
  int t = blockIdx.x;
  if (sortv[t] != rank) return;
  reprs[t * 256 + threadIdx.x] += encCLS[t * 256 + threadIdx.x];
}

__global__ void writeout_k(const float* __restrict__ reprs, float* __restrict__ out){
  int i = blockIdx.x * 256 + threadIdx.x;
  out[i] = reprs[i];
}

// One block = one term, 4 waves, all 4 layers fused. X stays in LDS (f32).
__global__ __launch_bounds__(256, 1)
void encode_k(const int* __restrict__ tokens, const void* __restrict__ pad,
              const void* __restrict__ refm, const int* __restrict__ boolflag,
              const float* __restrict__ storage, const float* __restrict__ emb,
              const u16* __restrict__ WqT, const u16* __restrict__ WkT,
              const u16* __restrict__ WvT, const u16* __restrict__ WoT,
              const u16* __restrict__ W1T, const float* __restrict__ b1,
              const u16* __restrict__ W2T, const float* __restrict__ b2,
              const float* __restrict__ ln1s, const float* __restrict__ ln1b,
              const float* __restrict__ ln2s, const float* __restrict__ ln2b,
              const int* __restrict__ sortv, int rank,
              float* __restrict__ outCLS)
{
  const int term = blockIdx.x;
  if (sortv && sortv[term] != rank) return;
  const int flag = *boolflag;

  __shared__ float sXf[64][268];   // X f32, stride 268 dw -> 2-way bank conflicts max
  __shared__ u16 sQKV[64][200];    // per-head-pair Q(64)|K(64)|V(64), pad 8
  __shared__ u16 sO[64][264];      // attention output
  __shared__ u16 sP[64][72];       // softmax probs, one head
  __shared__ float sStat[64][8];   // LN cross-wave partials
  __shared__ float sMask[64];      // additive key mask

  u16 (*sH)[136] = reinterpret_cast<u16(*)[136]>(&sQKV[0][0]); // FFN hidden chunk (aliases sQKV)

  const int tid = threadIdx.x;
  const int w = tid >> 6, lane = tid & 63, lg = lane >> 4, li = lane & 15;
  const f32x4 zero4 = {0.f, 0.f, 0.f, 0.f};

  if (tid < 64) sMask[tid] = getb(pad, term * 64 + tid, flag) ? 0.f : -1e9f;

  // build X: refmask ? storage[refids] : sum of 3 embeddings (all f32 sources)
  for (int s = 0; s < 64; ++s){
    float v;
    if (getb(refm, term * 64 + s, flag)){
      int rid = tokens[(term * 64 + s) * 3 + 1];
      v = storage[rid * 256 + tid];
    } else {
      int t0 = tokens[(term * 64 + s) * 3 + 0];
      int t1 = tokens[(term * 64 + s) * 3 + 1];
      int t2 = tokens[(term * 64 + s) * 3 + 2];
      v = emb[(0 * 2048 + t0) * 256 + tid]
        + emb[(1 * 2048 + t1) * 256 + tid]
        + emb[(2 * 2048 + t2) * 256 + tid];
    }
    sXf[s][tid] = v;
  }
  __syncthreads();

  for (int l = 0; l < 4; ++l){
    // ================= attention =================
    for (int hp = 0; hp < 4; ++hp){   // head pairs
      // QKV GEMM: local cols 0..191 = Q2|K2|V2; wave w owns cols [48w,48w+48)
      f32x4 acc[4][3];
      #pragma unroll
      for (int rt = 0; rt < 4; ++rt)
        #pragma unroll
        for (int c = 0; c < 3; ++c) acc[rt][c] = zero4;

      const u16* bptr[3];
      #pragma unroll
      for (int ctl = 0; ctl < 3; ++ctl){
        int c = 48 * w + 16 * ctl;
        int mm = c >> 6;                      // 0:Q 1:K 2:V (16-col tile never crosses 64)
        int gcol = hp * 64 + (c & 63) + li;
        const u16* Wt = (mm == 0) ? WqT : ((mm == 1) ? WkT : WvT);
        bptr[ctl] = Wt + ((size_t)(l * 256 + gcol)) * 256 + 8 * lg;
      }
      for (int kt = 0; kt < 8; ++kt){
        bf16x8 a[4];
        #pragma unroll
        for (int rt = 0; rt < 4; ++rt) a[rt] = ldx8(&sXf[16*rt + li][32*kt + 8*lg]);
        #pragma unroll
        for (int ctl = 0; ctl < 3; ++ctl){
          bf16x8 b = *(const bf16x8*)(bptr[ctl] + 32 * kt);
          #pragma unroll
          for (int rt = 0; rt < 4; ++rt)
            acc[rt][ctl] = __builtin_amdgcn_mfma_f32_16x16x32_bf16(a[rt], b, acc[rt][ctl], 0, 0, 0);
        }
      }
      __syncthreads();   // previous heads done reading sQKV
      #pragma unroll
      for (int rt = 0; rt < 4; ++rt)
        #pragma unroll
        for (int ctl = 0; ctl < 3; ++ctl)
          #pragma unroll
          for (int r = 0; r < 4; ++r)
            sQKV[16*rt + 4*lg + r][48*w + 16*ctl + li] = (u16)f2bf(acc[rt][ctl][r]);
      __syncthreads();

      for (int hh = 0; hh < 2; ++hh){
        const int qo = 32*hh, ko = 64 + 32*hh, vo = 128 + 32*hh;
        // S = Q K^T / sqrt(HD) + mask ; wave w owns q rows [16w,16w+16)
        bf16x8 aq = *(const bf16x8*)&sQKV[16*w + li][qo + 8*lg];
        f32x4 sc[4];
        #pragma unroll
        for (int ct = 0; ct < 4; ++ct){
          bf16x8 bk = *(const bf16x8*)&sQKV[16*ct + li][ko + 8*lg];
          sc[ct] = __builtin_amdgcn_mfma_f32_16x16x32_bf16(aq, bk, zero4, 0, 0, 0);
        }
        float sv[4][4];
        #pragma unroll
        for (int ct = 0; ct < 4; ++ct){
          float mk = sMask[16*ct + li];
          #pragma unroll
          for (int r = 0; r < 4; ++r) sv[ct][r] = sc[ct][r] * 0.17677669529663687f + mk;
        }
        #pragma unroll
        for (int r = 0; r < 4; ++r){
          float m = fmaxf(fmaxf(sv[0][r], sv[1][r]), fmaxf(sv[2][r], sv[3][r]));
          #pragma unroll
          for (int o = 1; o < 16; o <<= 1) m = fmaxf(m, __shfl_xor(m, o, 64));
          float s0 = 0.f;
          #pragma unroll
          for (int ct = 0; ct < 4; ++ct){ float e = __expf(sv[ct][r] - m); sv[ct][r] = e; s0 += e; }
          #pragma unroll
          for (int o = 1; o < 16; o <<= 1) s0 += __shfl_xor(s0, o, 64);
          float inv = 1.f / s0;
          #pragma unroll
          for (int ct = 0; ct < 4; ++ct) sv[ct][r] *= inv;
        }
        #pragma unroll
        for (int ct = 0; ct < 4; ++ct)
          #pragma unroll
          for (int r = 0; r < 4; ++r)
            sP[16*w + 4*lg + r][16*ct + li] = (u16)f2bf(sv[ct][r]);
        __syncthreads();
        // O_h = P @ V_h
        f32x4 oa[2] = {zero4, zero4};
        #pragma unroll
        for (int kt = 0; kt < 2; ++kt){
          bf16x8 ap = *(const bf16x8*)&sP[16*w + li][32*kt + 8*lg];
          #pragma unroll
          for (int ct = 0; ct < 2; ++ct){
            bf16x8 bv;
            #pragma unroll
            for (int j = 0; j < 8; ++j) bv[j] = (short)sQKV[32*kt + 8*lg + j][vo + 16*ct + li];
            oa[ct] = __builtin_amdgcn_mfma_f32_16x16x32_bf16(ap, bv, oa[ct], 0, 0, 0);
          }
        }
        const int h = 2*hp + hh;
        #pragma unroll
        for (int ct = 0; ct < 2; ++ct)
          #pragma unroll
          for (int r = 0; r < 4; ++r)
            sO[16*w + 4*lg + r][32*h + 16*ct + li] = (u16)f2bf(oa[ct][r]);
        __syncthreads();
      }
    }
    // ================= G = O @ Wo, residual, LN1 =================
    {
      f32x4 ga[4][4];
      #pragma unroll
      for (int rt = 0; rt < 4; ++rt)
        #pragma unroll
        for (int c = 0; c < 4; ++c) ga[rt][c] = zero4;
      const u16* wop = WoT + ((size_t)(l * 256 + 64*w + li)) * 256 + 8*lg;
      for (int kt = 0; kt < 8; ++kt){
        bf16x8 a[4];
        #pragma unroll
        for (int rt = 0; rt < 4; ++rt) a[rt] = *(const bf16x8*)&sO[16*rt + li][32*kt + 8*lg];
        #pragma unroll
        for (int ctl = 0; ctl < 4; ++ctl){
          bf16x8 b = *(const bf16x8*)(wop + (size_t)ctl * 16 * 256 + 32*kt);
          #pragma unroll
          for (int rt = 0; rt < 4; ++rt)
            ga[rt][ctl] = __builtin_amdgcn_mfma_f32_16x16x32_bf16(a[rt], b, ga[rt][ctl], 0, 0, 0);
        }
      }
      float s1v[4][4], s2v[4][4];
      #pragma unroll
      for (int rt = 0; rt < 4; ++rt)
        #pragma unroll
        for (int r = 0; r < 4; ++r){
          float t1 = 0.f, t2 = 0.f;
          #pragma unroll
          for (int ctl = 0; ctl < 4; ++ctl){
            float y = ga[rt][ctl][r] + sXf[16*rt + 4*lg + r][64*w + 16*ctl + li];
            ga[rt][ctl][r] = y; t1 += y; t2 += y * y;
          }
          #pragma unroll
          for (int o = 1; o < 16; o <<= 1){ t1 += __shfl_xor(t1, o, 64); t2 += __shfl_xor(t2, o, 64); }
          s1v[rt][r] = t1; s2v[rt][r] = t2;
        }
      if (li == 0){
        #pragma unroll
        for (int rt = 0; rt < 4; ++rt)
          #pragma unroll
          for (int r = 0; r < 4; ++r){
            sStat[16*rt + 4*lg + r][w] = s1v[rt][r];
            sStat[16*rt + 4*lg + r][4 + w] = s2v[rt][r];
          }
      }
      __syncthreads();
      #pragma unroll
      for (int rt = 0; rt < 4; ++rt)
        #pragma unroll
        for (int r = 0; r < 4; ++r){
          int row = 16*rt + 4*lg + r;
          float su = sStat[row][0] + sStat[row][1] + sStat[row][2] + sStat[row][3];
          float sq = sStat[row][4] + sStat[row][5] + sStat[row][6] + sStat[row][7];
          float mean = su * (1.f / 256.f);
          float var = sq * (1.f / 256.f) - mean * mean;
          float rs = rsqrtf(var + 1e-5f);
          #pragma unroll
          for (int ctl = 0; ctl < 4; ++ctl){
            int col = 64*w + 16*ctl + li;
            float g = ln1s[l * 256 + col], bb = ln1b[l * 256 + col];
            sXf[row][col] = (ga[rt][ctl][r] - mean) * rs * g + bb;
          }
        }
      __syncthreads();
    }
    // ================= FFN (hidden chunked by 128) + LN2 =================
    {
      f32x4 fa[4][4];
      #pragma unroll
      for (int rt = 0; rt < 4; ++rt)
        #pragma unroll
        for (int c = 0; c < 4; ++c) fa[rt][c] = zero4;
      for (int ch = 0; ch < 8; ++ch){
        f32x4 ha[4][2];
        #pragma unroll
        for (int rt = 0; rt < 4; ++rt){ ha[rt][0] = zero4; ha[rt][1] = zero4; }
        const u16* w1p = W1T + ((size_t)(l * 1024 + 128*ch + 32*w + li)) * 256 + 8*lg;
        for (int kt = 0; kt < 8; ++kt){
          bf16x8 a[4];
          #pragma unroll
          for (int rt = 0; rt < 4; ++rt) a[rt] = ldx8(&sXf[16*rt + li][32*kt + 8*lg]);
          #pragma unroll
          for (int ctl = 0; ctl < 2; ++ctl){
            bf16x8 b = *(const bf16x8*)(w1p + (size_t)ctl * 16 * 256 + 32*kt);
            #pragma unroll
            for (int rt = 0; rt < 4; ++rt)
              ha[rt][ctl] = __builtin_amdgcn_mfma_f32_16x16x32_bf16(a[rt], b, ha[rt][ctl], 0, 0, 0);
          }
        }
        __syncthreads();   // previous chunk's GEMM2 done reading sH
        #pragma unroll
        for (int rt = 0; rt < 4; ++rt)
          #pragma unroll
          for (int ctl = 0; ctl < 2; ++ctl)
            #pragma unroll
            for (int r = 0; r < 4; ++r){
              int n = 128*ch + 32*w + 16*ctl + li;
              float v = ha[rt][ctl][r] + b1[l * 1024 + n];
              sH[16*rt + 4*lg + r][32*w + 16*ctl + li] = (u16)f2bf(fmaxf(v, 0.f));
            }
        __syncthreads();
        const u16* w2p = W2T + ((size_t)(l * 256 + 64*w + li)) * 1024 + 8*lg;
        for (int kt = 0; kt < 4; ++kt){
          bf16x8 a[4];
          #pragma unroll
          for (int rt = 0; rt < 4; ++rt) a[rt] = *(const bf16x8*)&sH[16*rt + li][32*kt + 8*lg];
          #pragma unroll
          for (int ctl = 0; ctl < 4; ++ctl){
            bf16x8 b = *(const bf16x8*)(w2p + (size_t)ctl * 16 * 1024 + 128*ch + 32*kt);
            #pragma unroll
            for (int rt = 0; rt < 4; ++rt)
              fa[rt][ctl] = __builtin_amdgcn_mfma_f32_16x16x32_bf16(a[rt], b, fa[rt][ctl], 0, 0, 0);
          }
        }
      }
      float s1v[4][4], s2v[4][4];
      #pragma unroll
      for (int rt = 0; rt < 4; ++rt)
        #pragma unroll
        for (int r = 0; r < 4; ++r){
          float t1 = 0.f, t2 = 0.f;
          #pragma unroll
          for (int ctl = 0; ctl < 4; ++ctl){
            int col = 64*w + 16*ctl + li;
            float y = fa[rt][ctl][r] + sXf[16*rt + 4*lg + r][col] + b2[l * 256 + col];
            fa[rt][ctl][r] = y; t1 += y; t2 += y * y;
          }
          #pragma unroll
          for (int o = 1; o < 16; o <<= 1){ t1 += __shfl_xor(t1, o, 64); t2 += __shfl_xor(t2, o, 64); }
          s1v[rt][r] = t1; s2v[rt][r] = t2;
        }
      if (li == 0){
        #pragma unroll
        for (int rt = 0; rt < 4; ++rt)
          #pragma unroll
          for (int r = 0; r < 4; ++r){
            sStat[16*rt + 4*lg + r][w] = s1v[rt][r];
            sStat[16*rt + 4*lg + r][4 + w] = s2v[rt][r];
          }
      }
      __syncthreads();
      #pragma unroll
      for (int rt = 0; rt < 4; ++rt)
        #pragma unroll
        for (int r = 0; r < 4; ++r){
          int row = 16*rt + 4*lg + r;
          float su = sStat[row][0] + sStat[row][1] + sStat[row][2] + sStat[row][3];
          float sq = sStat[row][4] + sStat[row][5] + sStat[row][6] + sStat[row][7];
          float mean = su * (1.f / 256.f);
          float var = sq * (1.f / 256.f) - mean * mean;
          float rs = rsqrtf(var + 1e-5f);
          #pragma unroll
          for (int ctl = 0; ctl < 4; ++ctl){
            int col = 64*w + 16*ctl + li;
            float g = ln2s[l * 256 + col], bb = ln2b[l * 256 + col];
            sXf[row][col] = (fa[rt][ctl][r] - mean) * rs * g + bb;
          }
        }
      __syncthreads();
    }
  }

  // CLS output (token 0)
  if (outCLS) outCLS[term * 256 + tid] = sXf[0][tid];
}

extern "C" void kernel_launch(void* const* d_in, const int* in_sizes, int n_in,
                              void* d_out, int out_size, void* d_ws, size_t ws_size,
                              hipStream_t stream)
{
  (void)in_sizes; (void)n_in; (void)out_size; (void)ws_size;
  const int* tokens_scope = (const int*)d_in[0];
  const int* tokens_hole  = (const int*)d_in[1];
  const void* pad_scope = d_in[2];
  const void* pad_hole  = d_in[3];
  const void* ref_scope = d_in[4];
  const void* ref_hole  = d_in[5];
  const int* scope_sort = (const int*)d_in[6];
  const int* scope_pos  = (const int*)d_in[7];
  const float* emb  = (const float*)d_in[8];
  const float* Wq   = (const float*)d_in[9];
  const float* Wk   = (const float*)d_in[10];
  const float* Wv   = (const float*)d_in[11];
  const float* Wo   = (const float*)d_in[12];
  const float* ln1s = (const float*)d_in[13];
  const float* ln1b = (const float*)d_in[14];
  const float* W1   = (const float*)d_in[15];
  const float* b1   = (const float*)d_in[16];
  const float* W2   = (const float*)d_in[17];
  const float* b2   = (const float*)d_in[18];
  const float* ln2s = (const float*)d_in[19];
  const float* ln2b = (const float*)d_in[20];

  char* p = (char*)d_ws;
  float* reprs  = (float*)p; p += (size_t)2048*256*4;
  float* encCLS = (float*)p; p += (size_t)2048*256*4;
  u16* WqT = (u16*)p; p += (size_t)4*256*256*2;
  u16* WkT = (u16*)p; p += (size_t)4*256*256*2;
  u16* WvT = (u16*)p; p += (size_t)4*256*256*2;
  u16* WoT = (u16*)p; p += (size_t)4*256*256*2;
  u16* W1T = (u16*)p; p += (size_t)4*256*1024*2;
  u16* W2T = (u16*)p; p += (size_t)4*256*1024*2;
  int* flag = (int*)p; p += 16;

  hipLaunchKernelGGL(detect_bool_k, dim3(1), dim3(1), 0, stream, pad_scope, flag);
  hipLaunchKernelGGL(transpose_k, dim3(1024), dim3(256), 0, stream, Wq, WqT, 256, 256);
  hipLaunchKernelGGL(transpose_k, dim3(1024), dim3(256), 0, stream, Wk, WkT, 256, 256);
  hipLaunchKernelGGL(transpose_k, dim3(1024), dim3(256), 0, stream, Wv, WvT, 256, 256);
  hipLaunchKernelGGL(transpose_k, dim3(1024), dim3(256), 0, stream, Wo, WoT, 256, 256);
  hipLaunchKernelGGL(transpose_k, dim3(4096), dim3(256), 0, stream, W1, W1T, 256, 1024);
  hipLaunchKernelGGL(transpose_k, dim3(4096), dim3(256), 0, stream, W2, W2T, 1024, 256);
  hipLaunchKernelGGL(pos_init_k, dim3(2048), dim3(256), 0, stream, scope_pos, reprs);

  for (int r = 0; r < 4; ++r){
    hipLaunchKernelGGL(encode_k, dim3(2048), dim3(256), 0, stream,
      tokens_scope, pad_scope, ref_scope, flag, reprs, emb,
      WqT, WkT, WvT, WoT, W1T, b1, W2T, b2, ln1s, ln1b, ln2s, ln2b,
      scope_sort, r, encCLS);
    hipLaunchKernelGGL(update_k, dim3(2048), dim3(256), 0, stream, scope_sort, encCLS, reprs, r);
  }
  hipLaunchKernelGGL(encode_k, dim3(512), dim3(256), 0, stream,
      tokens_hole, pad_hole, ref_hole, flag, reprs, emb,
      WqT, WkT, WvT, WoT, W1T, b1, W2T, b2, ln1s, ln1b, ln2s, ln2b,
      (const int*)nullptr, 0, (float*)d_out + (size_t)2048*256);
  hipLaunchKernelGGL(writeout_k, dim3(2048), dim3(256), 0, stream, reprs, (float*)d_out);
}

// Round 3
// 6035.884 us; speedup vs baseline: 1.3842x; 1.3842x over previous
//
#include <hip/hip_runtime.h>
#include <stdint.h>
#include <math.h>

typedef __attribute__((ext_vector_type(8))) short bf16x8;
typedef __attribute__((ext_vector_type(4))) float f32x4;
typedef unsigned short u16;

__device__ __forceinline__ short f2bf(float f){
  union { float f; uint32_t u; } v; v.f = f;
  uint32_t r = v.u + 0x7FFFu + ((v.u >> 16) & 1u);
  return (short)(r >> 16);
}
__device__ __forceinline__ float bf2f(u16 b){
  union { uint32_t u; float f; } v; v.u = ((uint32_t)b) << 16; return v.f;
}
// bool inputs may arrive as uint8 (numpy bool) or int32; runtime-detected flag selects.
__device__ __forceinline__ bool getb(const void* p, int i, int flag){
  if (flag) return ((const unsigned char*)p)[i] != 0;
  return ((const int*)p)[i] != 0;
}
// XOR-swizzled offset into the bf16 X buffer [64 rows][256 cols]
__device__ __forceinline__ int xoff(int row, int col){
  int g = (col >> 3) ^ (row & 7);
  return row * 256 + (g << 3) + (col & 7);
}

__global__ void detect_bool_k(const void* pad, int* flag){
  const unsigned char* b = (const unsigned char*)pad;
  int f = 0;
  for (int i = 1; i < 64; ++i) if (i & 3) f |= (b[i] != 0) ? 1 : 0;
  *flag = f;
}

__global__ void transpose_k(const float* __restrict__ src, u16* __restrict__ dst, int R, int C){
  // src f32 [mats][R][C] -> dst bf16 [mats][C][R]; grid*256 == mats*R*C exactly
  long idx = (long)blockIdx.x * blockDim.x + threadIdx.x;
  int r = (int)(idx % R);
  long t = idx / R;
  int c = (int)(t % C);
  int m = (int)(t / C);
  dst[idx] = (u16)f2bf(src[((long)m * R + r) * C + c]);
}

__global__ void pos_init_k(const int* __restrict__ pos, float* __restrict__ reprs){
  int n = blockIdx.x, d = threadIdx.x;
  double p = (double)pos[n];
  int i = (d < 128) ? d : d - 128;
  double ang = p / pow(500.0, (2.0 * (double)i) / 256.0);
  reprs[n * 256 + d] = (d < 128) ? (float)sin(ang) : (float)cos(ang);
}

__global__ void update_k(const int* __restrict__ sortv, const float* __restrict__ encCLS,
                         float* __restrict__ reprs, int rank){
  int t = blockIdx.x;
  if (sortv[t] != rank) return;
  reprs[t * 256 + threadIdx.x] += encCLS[t * 256 + threadIdx.x];
}

__global__ void writeout_k(const float* __restrict__ reprs, float* __restrict__ out){
  int i = blockIdx.x * 256 + threadIdx.x;
  out[i] = reprs[i];
}

// One block = one term, 4 waves, all 4 layers fused.
// X residual lives in registers (xres); LDS holds bf16 X (swizzled) for MFMA A-frags.
// LDS total 80128 B -> 2 blocks/CU; VGPR capped at 256 via launch_bounds(256,2).
__global__ __launch_bounds__(256, 2)
void encode_k(const int* __restrict__ tokens, const void* __restrict__ pad,
              const void* __restrict__ refm, const int* __restrict__ boolflag,
              const float* __restrict__ storage, const float* __restrict__ emb,
              const u16* __restrict__ WqT, const u16* __restrict__ WkT,
              const u16* __restrict__ WvT, const u16* __restrict__ WoT,
              const u16* __restrict__ W1T, const float* __restrict__ b1,
              const u16* __restrict__ W2T, const float* __restrict__ b2,
              const float* __restrict__ ln1s, const float* __restrict__ ln1b,
              const float* __restrict__ ln2s, const float* __restrict__ ln2b,
              const int* __restrict__ sortv, int rank,
              float* __restrict__ outCLS)
{
  const int term = blockIdx.x;
  if (sortv && sortv[term] != rank) return;
  const int flag = *boolflag;

  __shared__ u16 sXb[64 * 256];    // bf16 X, XOR-swizzled (32 KB)
  __shared__ u16 sQK[64][136];     // Q cols 0..63 | K cols 64..127, pad 8 (17 KB)
  __shared__ u16 sVT[64][72];      // V^T for current head pair: [vcol][krow] (9 KB)
  __shared__ u16 sO[64][72];       // O cols of current head pair (9 KB)
  __shared__ u16 sP[64][72];       // softmax probs, one head (9 KB)
  __shared__ float sStat[64][8];   // LN cross-wave partials (2 KB)
  __shared__ float sMask[64];

  u16 (*sH)[136] = sQK;            // FFN hidden chunk aliases sQK

  const int tid = threadIdx.x;
  const int w = tid >> 6, lane = tid & 63, lg = lane >> 4, li = lane & 15;
  const f32x4 zero4 = {0.f, 0.f, 0.f, 0.f};

  if (tid < 64) sMask[tid] = getb(pad, term * 64 + tid, flag) ? 0.f : -1e9f;

  // build X (bf16 into sXb): refmask ? storage[refids] : sum of 3 embeddings
  for (int s = 0; s < 64; ++s){
    float v;
    if (getb(refm, term * 64 + s, flag)){
      int rid = tokens[(term * 64 + s) * 3 + 1];
      v = storage[rid * 256 + tid];
    } else {
      int t0 = tokens[(term * 64 + s) * 3 + 0];
      int t1 = tokens[(term * 64 + s) * 3 + 1];
      int t2 = tokens[(term * 64 + s) * 3 + 2];
      v = emb[(0 * 2048 + t0) * 256 + tid]
        + emb[(1 * 2048 + t1) * 256 + tid]
        + emb[(2 * 2048 + t2) * 256 + tid];
    }
    sXb[xoff(s, tid)] = (u16)f2bf(v);
  }
  __syncthreads();

  // X residual in registers at this thread's C-fragment positions
  float xres[4][4][4];
  #pragma unroll
  for (int rt = 0; rt < 4; ++rt)
    #pragma unroll
    for (int ctl = 0; ctl < 4; ++ctl)
      #pragma unroll
      for (int r = 0; r < 4; ++r)
        xres[rt][ctl][r] = bf2f(sXb[xoff(16*rt + 4*lg + r, 64*w + 16*ctl + li)]);

  for (int l = 0; l < 4; ++l){
    // ================= attention (incremental Wo accumulate) =================
    f32x4 ga[4][4];
    #pragma unroll
    for (int rt = 0; rt < 4; ++rt)
      #pragma unroll
      for (int c = 0; c < 4; ++c) ga[rt][c] = zero4;

    for (int hp = 0; hp < 4; ++hp){   // head pairs
      // QKV GEMM: block-local cols 0..191 = Q(64)|K(64)|V(64) of this pair
      f32x4 acc[4][3];
      #pragma unroll
      for (int rt = 0; rt < 4; ++rt)
        #pragma unroll
        for (int c = 0; c < 3; ++c) acc[rt][c] = zero4;

      const u16* bptr[3];
      #pragma unroll
      for (int ctl = 0; ctl < 3; ++ctl){
        int c = 48 * w + 16 * ctl;
        int mm = c >> 6;                      // 0:Q 1:K 2:V
        int gcol = hp * 64 + (c & 63) + li;
        const u16* Wt = (mm == 0) ? WqT : ((mm == 1) ? WkT : WvT);
        bptr[ctl] = Wt + ((size_t)(l * 256 + gcol)) * 256 + 8 * lg;
      }
      for (int kt = 0; kt < 8; ++kt){
        bf16x8 a[4];
        #pragma unroll
        for (int rt = 0; rt < 4; ++rt)
          a[rt] = *(const bf16x8*)&sXb[(16*rt + li) * 256 + (((4*kt + lg) ^ (li & 7)) << 3)];
        #pragma unroll
        for (int ctl = 0; ctl < 3; ++ctl){
          bf16x8 b = *(const bf16x8*)(bptr[ctl] + 32 * kt);
          #pragma unroll
          for (int rt = 0; rt < 4; ++rt)
            acc[rt][ctl] = __builtin_amdgcn_mfma_f32_16x16x32_bf16(a[rt], b, acc[rt][ctl], 0, 0, 0);
        }
      }
      __syncthreads();   // previous hp's readers of sQK/sVT/sO done
      #pragma unroll
      for (int rt = 0; rt < 4; ++rt)
        #pragma unroll
        for (int ctl = 0; ctl < 3; ++ctl){
          int c = 48*w + 16*ctl;
          #pragma unroll
          for (int r = 0; r < 4; ++r){
            int row = 16*rt + 4*lg + r;
            u16 val = (u16)f2bf(acc[rt][ctl][r]);
            if (c < 128) sQK[row][c + li] = val;           // Q at 0..63, K at 64..127
            else         sVT[c + li - 128][row] = val;     // V transposed
          }
        }
      __syncthreads();

      for (int hh = 0; hh < 2; ++hh){
        // S = Q K^T / sqrt(HD) + mask ; wave w owns q rows [16w,16w+16)
        bf16x8 aq = *(const bf16x8*)&sQK[16*w + li][32*hh + 8*lg];
        f32x4 sc[4];
        #pragma unroll
        for (int ct = 0; ct < 4; ++ct){
          bf16x8 bk = *(const bf16x8*)&sQK[16*ct + li][64 + 32*hh + 8*lg];
          sc[ct] = __builtin_amdgcn_mfma_f32_16x16x32_bf16(aq, bk, zero4, 0, 0, 0);
        }
        float sv[4][4];
        #pragma unroll
        for (int ct = 0; ct < 4; ++ct){
          float mk = sMask[16*ct + li];
          #pragma unroll
          for (int r = 0; r < 4; ++r) sv[ct][r] = sc[ct][r] * 0.17677669529663687f + mk;
        }
        #pragma unroll
        for (int r = 0; r < 4; ++r){
          float m = fmaxf(fmaxf(sv[0][r], sv[1][r]), fmaxf(sv[2][r], sv[3][r]));
          #pragma unroll
          for (int o = 1; o < 16; o <<= 1) m = fmaxf(m, __shfl_xor(m, o, 64));
          float s0 = 0.f;
          #pragma unroll
          for (int ct = 0; ct < 4; ++ct){ float e = __expf(sv[ct][r] - m); sv[ct][r] = e; s0 += e; }
          #pragma unroll
          for (int o = 1; o < 16; o <<= 1) s0 += __shfl_xor(s0, o, 64);
          float inv = 1.f / s0;
          #pragma unroll
          for (int ct = 0; ct < 4; ++ct) sv[ct][r] *= inv;
        }
        __syncthreads();   // prior PV readers of sP done
        #pragma unroll
        for (int ct = 0; ct < 4; ++ct)
          #pragma unroll
          for (int r = 0; r < 4; ++r)
            sP[16*w + 4*lg + r][16*ct + li] = (u16)f2bf(sv[ct][r]);
        __syncthreads();
        // O_h = P @ V_h  (V^T direct b128 reads)
        f32x4 oa[2] = {zero4, zero4};
        #pragma unroll
        for (int kt = 0; kt < 2; ++kt){
          bf16x8 ap = *(const bf16x8*)&sP[16*w + li][32*kt + 8*lg];
          #pragma unroll
          for (int ct = 0; ct < 2; ++ct){
            bf16x8 bv = *(const bf16x8*)&sVT[32*hh + 16*ct + li][32*kt + 8*lg];
            oa[ct] = __builtin_amdgcn_mfma_f32_16x16x32_bf16(ap, bv, oa[ct], 0, 0, 0);
          }
        }
        #pragma unroll
        for (int ct = 0; ct < 2; ++ct)
          #pragma unroll
          for (int r = 0; r < 4; ++r)
            sO[16*w + 4*lg + r][32*hh + 16*ct + li] = (u16)f2bf(oa[ct][r]);
      }
      __syncthreads();   // sO complete for this hp
      // partial Wo: ga += O[:, 64hp:64hp+64) @ Wo[64hp:64hp+64, :]
      #pragma unroll
      for (int kt2 = 0; kt2 < 2; ++kt2){
        bf16x8 a[4];
        #pragma unroll
        for (int rt = 0; rt < 4; ++rt)
          a[rt] = *(const bf16x8*)&sO[16*rt + li][32*kt2 + 8*lg];
        #pragma unroll
        for (int ctl = 0; ctl < 4; ++ctl){
          const u16* bp = WoT + ((size_t)(l*256 + 64*w + 16*ctl + li)) * 256 + 64*hp + 32*kt2 + 8*lg;
          bf16x8 b = *(const bf16x8*)bp;
          #pragma unroll
          for (int rt = 0; rt < 4; ++rt)
            ga[rt][ctl] = __builtin_amdgcn_mfma_f32_16x16x32_bf16(a[rt], b, ga[rt][ctl], 0, 0, 0);
        }
      }
    } // hp

    // ================= residual + LN1 (regs -> sXb) =================
    {
      float s1v[4][4], s2v[4][4];
      #pragma unroll
      for (int rt = 0; rt < 4; ++rt)
        #pragma unroll
        for (int r = 0; r < 4; ++r){
          float t1 = 0.f, t2 = 0.f;
          #pragma unroll
          for (int ctl = 0; ctl < 4; ++ctl){
            float y = ga[rt][ctl][r] + xres[rt][ctl][r];
            ga[rt][ctl][r] = y; t1 += y; t2 += y * y;
          }
          #pragma unroll
          for (int o = 1; o < 16; o <<= 1){ t1 += __shfl_xor(t1, o, 64); t2 += __shfl_xor(t2, o, 64); }
          s1v[rt][r] = t1; s2v[rt][r] = t2;
        }
      if (li == 0){
        #pragma unroll
        for (int rt = 0; rt < 4; ++rt)
          #pragma unroll
          for (int r = 0; r < 4; ++r){
            sStat[16*rt + 4*lg + r][w] = s1v[rt][r];
            sStat[16*rt + 4*lg + r][4 + w] = s2v[rt][r];
          }
      }
      __syncthreads();
      #pragma unroll
      for (int rt = 0; rt < 4; ++rt)
        #pragma unroll
        for (int r = 0; r < 4; ++r){
          int row = 16*rt + 4*lg + r;
          float su = sStat[row][0] + sStat[row][1] + sStat[row][2] + sStat[row][3];
          float sq = sStat[row][4] + sStat[row][5] + sStat[row][6] + sStat[row][7];
          float mean = su * (1.f / 256.f);
          float var = sq * (1.f / 256.f) - mean * mean;
          float rs = rsqrtf(var + 1e-5f);
          #pragma unroll
          for (int ctl = 0; ctl < 4; ++ctl){
            int col = 64*w + 16*ctl + li;
            float nv = (ga[rt][ctl][r] - mean) * rs * ln1s[l*256 + col] + ln1b[l*256 + col];
            xres[rt][ctl][r] = nv;                       // hmm: overwritten below per ctl -> need [ctl] index
            sXb[xoff(row, col)] = (u16)f2bf(nv);
          }
        }
      __syncthreads();
    }
    // fix: xres assignment above already indexed [rt][ctl][r] correctly via loop var

    // ================= FFN (hidden chunked by 128) + LN2 =================
    {
      f32x4 fa[4][4];
      #pragma unroll
      for (int rt = 0; rt < 4; ++rt)
        #pragma unroll
        for (int c = 0; c < 4; ++c) fa[rt][c] = zero4;
      for (int ch = 0; ch < 8; ++ch){
        f32x4 ha[4][2];
        #pragma unroll
        for (int rt = 0; rt < 4; ++rt){ ha[rt][0] = zero4; ha[rt][1] = zero4; }
        const u16* w1p = W1T + ((size_t)(l * 1024 + 128*ch + 32*w + li)) * 256 + 8*lg;
        for (int kt = 0; kt < 8; ++kt){
          bf16x8 a[4];
          #pragma unroll
          for (int rt = 0; rt < 4; ++rt)
            a[rt] = *(const bf16x8*)&sXb[(16*rt + li) * 256 + (((4*kt + lg) ^ (li & 7)) << 3)];
          #pragma unroll
          for (int ctl = 0; ctl < 2; ++ctl){
            bf16x8 b = *(const bf16x8*)(w1p + (size_t)ctl * 16 * 256 + 32*kt);
            #pragma unroll
            for (int rt = 0; rt < 4; ++rt)
              ha[rt][ctl] = __builtin_amdgcn_mfma_f32_16x16x32_bf16(a[rt], b, ha[rt][ctl], 0, 0, 0);
          }
        }
        __syncthreads();   // previous chunk's GEMM2 done reading sH
        #pragma unroll
        for (int rt = 0; rt < 4; ++rt)
          #pragma unroll
          for (int ctl = 0; ctl < 2; ++ctl)
            #pragma unroll
            for (int r = 0; r < 4; ++r){
              int n = 128*ch + 32*w + 16*ctl + li;
              float v = ha[rt][ctl][r] + b1[l * 1024 + n];
              sH[16*rt + 4*lg + r][32*w + 16*ctl + li] = (u16)f2bf(fmaxf(v, 0.f));
            }
        __syncthreads();
        const u16* w2p = W2T + ((size_t)(l * 256 + 64*w + li)) * 1024 + 8*lg;
        for (int kt = 0; kt < 4; ++kt){
          bf16x8 a[4];
          #pragma unroll
          for (int rt = 0; rt < 4; ++rt) a[rt] = *(const bf16x8*)&sH[16*rt + li][32*kt + 8*lg];
          #pragma unroll
          for (int ctl = 0; ctl < 4; ++ctl){
            bf16x8 b = *(const bf16x8*)(w2p + (size_t)ctl * 16 * 1024 + 128*ch + 32*kt);
            #pragma unroll
            for (int rt = 0; rt < 4; ++rt)
              fa[rt][ctl] = __builtin_amdgcn_mfma_f32_16x16x32_bf16(a[rt], b, fa[rt][ctl], 0, 0, 0);
          }
        }
      }
      float s1v[4][4], s2v[4][4];
      #pragma unroll
      for (int rt = 0; rt < 4; ++rt)
        #pragma unroll
        for (int r = 0; r < 4; ++r){
          float t1 = 0.f, t2 = 0.f;
          #pragma unroll
          for (int ctl = 0; ctl < 4; ++ctl){
            int col = 64*w + 16*ctl + li;
            float y = fa[rt][ctl][r] + xres[rt][ctl][r] + b2[l * 256 + col];
            fa[rt][ctl][r] = y; t1 += y; t2 += y * y;
          }
          #pragma unroll
          for (int o = 1; o < 16; o <<= 1){ t1 += __shfl_xor(t1, o, 64); t2 += __shfl_xor(t2, o, 64); }
          s1v[rt][r] = t1; s2v[rt][r] = t2;
        }
      if (li == 0){
        #pragma unroll
        for (int rt = 0; rt < 4; ++rt)
          #pragma unroll
          for (int r = 0; r < 4; ++r){
            sStat[16*rt + 4*lg + r][w] = s1v[rt][r];
            sStat[16*rt + 4*lg + r][4 + w] = s2v[rt][r];
          }
      }
      __syncthreads();
      #pragma unroll
      for (int rt = 0; rt < 4; ++rt)
        #pragma unroll
        for (int r = 0; r < 4; ++r){
          int row = 16*rt + 4*lg + r;
          float su = sStat[row][0] + sStat[row][1] + sStat[row][2] + sStat[row][3];
          float sq = sStat[row][4] + sStat[row][5] + sStat[row][6] + sStat[row][7];
          float mean = su * (1.f / 256.f);
          float var = sq * (1.f / 256.f) - mean * mean;
          float rs = rsqrtf(var + 1e-5f);
          #pragma unroll
          for (int ctl = 0; ctl < 4; ++ctl){
            int col = 64*w + 16*ctl + li;
            float nv = (fa[rt][ctl][r] - mean) * rs * ln2s[l*256 + col] + ln2b[l*256 + col];
            xres[rt][ctl][r] = nv;
            sXb[xoff(row, col)] = (u16)f2bf(nv);
            if (l == 3 && outCLS && row == 0) outCLS[term * 256 + col] = nv;
          }
        }
      __syncthreads();
    }
  }
}

extern "C" void kernel_launch(void* const* d_in, const int* in_sizes, int n_in,
                              void* d_out, int out_size, void* d_ws, size_t ws_size,
                              hipStream_t stream)
{
  (void)in_sizes; (void)n_in; (void)out_size; (void)ws_size;
  const int* tokens_scope = (const int*)d_in[0];
  const int* tokens_hole  = (const int*)d_in[1];
  const void* pad_scope = d_in[2];
  const void* pad_hole  = d_in[3];
  const void* ref_scope = d_in[4];
  const void* ref_hole  = d_in[5];
  const int* scope_sort = (const int*)d_in[6];
  const int* scope_pos  = (const int*)d_in[7];
  const float* emb  = (const float*)d_in[8];
  const float* Wq   = (const float*)d_in[9];
  const float* Wk   = (const float*)d_in[10];
  const float* Wv   = (const float*)d_in[11];
  const float* Wo   = (const float*)d_in[12];
  const float* ln1s = (const float*)d_in[13];
  const float* ln1b = (const float*)d_in[14];
  const float* W1   = (const float*)d_in[15];
  const float* b1   = (const float*)d_in[16];
  const float* W2   = (const float*)d_in[17];
  const float* b2   = (const float*)d_in[18];
  const float* ln2s = (const float*)d_in[19];
  const float* ln2b = (const float*)d_in[20];

  char* p = (char*)d_ws;
  float* reprs  = (float*)p; p += (size_t)2048*256*4;
  float* encCLS = (float*)p; p += (size_t)2048*256*4;
  u16* WqT = (u16*)p; p += (size_t)4*256*256*2;
  u16* WkT = (u16*)p; p += (size_t)4*256*256*2;
  u16* WvT = (u16*)p; p += (size_t)4*256*256*2;
  u16* WoT = (u16*)p; p += (size_t)4*256*256*2;
  u16* W1T = (u16*)p; p += (size_t)4*256*1024*2;
  u16* W2T = (u16*)p; p += (size_t)4*256*1024*2;
  int* flag = (int*)p; p += 16;

  hipLaunchKernelGGL(detect_bool_k, dim3(1), dim3(1), 0, stream, pad_scope, flag);
  hipLaunchKernelGGL(transpose_k, dim3(1024), dim3(256), 0, stream, Wq, WqT, 256, 256);
  hipLaunchKernelGGL(transpose_k, dim3(1024), dim3(256), 0, stream, Wk, WkT, 256, 256);
  hipLaunchKernelGGL(transpose_k, dim3(1024), dim3(256), 0, stream, Wv, WvT, 256, 256);
  hipLaunchKernelGGL(transpose_k, dim3(1024), dim3(256), 0, stream, Wo, WoT, 256, 256);
  hipLaunchKernelGGL(transpose_k, dim3(4096), dim3(256), 0, stream, W1, W1T, 256, 1024);
  hipLaunchKernelGGL(transpose_k, dim3(4096), dim3(256), 0, stream, W2, W2T, 1024, 256);
  hipLaunchKernelGGL(pos_init_k, dim3(2048), dim3(256), 0, stream, scope_pos, reprs);

  for (int r = 0; r < 4; ++r){
    hipLaunchKernelGGL(encode_k, dim3(2048), dim3(256), 0, stream,
      tokens_scope, pad_scope, ref_scope, flag, reprs, emb,
      WqT, WkT, WvT, WoT, W1T, b1, W2T, b2, ln1s, ln1b, ln2s, ln2b,
      scope_sort, r, encCLS);
    hipLaunchKernelGGL(update_k, dim3(2048), dim3(256), 0, stream, scope_sort, encCLS, reprs, r);
  }
  hipLaunchKernelGGL(encode_k, dim3(512), dim3(256), 0, stream,
      tokens_hole, pad_hole, ref_hole, flag, reprs, emb,
      WqT, WkT, WvT, WoT, W1T, b1, W2T, b2, ln1s, ln1b, ln2s, ln2b,
      (const int*)nullptr, 0, (float*)d_out + (size_t)2048*256);
  hipLaunchKernelGGL(writeout_k, dim3(2048), dim3(256), 0, stream, reprs, (float*)d_out);
}

// Round 4
// 5279.983 us; speedup vs baseline: 1.5824x; 1.1432x over previous
//
#include <hip/hip_runtime.h>
#include <stdint.h>
#include <math.h>

typedef __attribute__((ext_vector_type(8))) short bf16x8;
typedef __attribute__((ext_vector_type(4))) short s16x4;
typedef __attribute__((ext_vector_type(4))) float f32x4;
typedef unsigned short u16;

__device__ __forceinline__ short f2bf(float f){
  union { float f; uint32_t u; } v; v.f = f;
  uint32_t r = v.u + 0x7FFFu + ((v.u >> 16) & 1u);
  return (short)(r >> 16);
}
__device__ __forceinline__ float bf2f(u16 b){
  union { uint32_t u; float f; } v; v.u = ((uint32_t)b) << 16; return v.f;
}
// bool inputs may arrive as uint8 (numpy bool) or int32; runtime-detected flag selects.
__device__ __forceinline__ bool getb(const void* p, int i, int flag){
  if (flag) return ((const unsigned char*)p)[i] != 0;
  return ((const int*)p)[i] != 0;
}
// XOR-swizzled offset into the bf16 X buffer [64 rows][256 cols]
__device__ __forceinline__ int xoff(int row, int col){
  int g = (col >> 3) ^ (row & 7);
  return row * 256 + (g << 3) + (col & 7);
}

__global__ void detect_bool_k(const void* pad, int* flag){
  const unsigned char* b = (const unsigned char*)pad;
  int f = 0;
  for (int i = 1; i < 64; ++i) if (i & 3) f |= (b[i] != 0) ? 1 : 0;
  *flag = f;
}

__global__ void transpose_k(const float* __restrict__ src, u16* __restrict__ dst, int R, int C){
  // src f32 [mats][R][C] -> dst bf16 [mats][C][R]; grid*256 == mats*R*C exactly
  long idx = (long)blockIdx.x * blockDim.x + threadIdx.x;
  int r = (int)(idx % R);
  long t = idx / R;
  int c = (int)(t % C);
  int m = (int)(t / C);
  dst[idx] = (u16)f2bf(src[((long)m * R + r) * C + c]);
}

__global__ void pos_init_k(const int* __restrict__ pos, float* __restrict__ reprs){
  int n = blockIdx.x, d = threadIdx.x;
  double p = (double)pos[n];
  int i = (d < 128) ? d : d - 128;
  double ang = p / pow(500.0, (2.0 * (double)i) / 256.0);
  reprs[n * 256 + d] = (d < 128) ? (float)sin(ang) : (float)cos(ang);
}

__global__ void update_k(const int* __restrict__ sortv, const float* __restrict__ encCLS,
                         float* __restrict__ reprs, int rank){
  int t = blockIdx.x;
  if (sortv[t] != rank) return;
  reprs[t * 256 + threadIdx.x] += encCLS[t * 256 + threadIdx.x];
}

__global__ void writeout_k(const float* __restrict__ reprs, float* __restrict__ out){
  int i = blockIdx.x * 256 + threadIdx.x;
  out[i] = reprs[i];
}

// One block = one term, 4 waves, all 4 layers fused.
// X residual in registers; bf16 X (XOR-swizzled) in LDS; minimal barriers:
//   per layer: 4x(post-scatter + sO-complete) + 2 (LN1) + 8 (FFN dbuf) + 2 (LN2) = 20.
// sP needs NO barriers (wave-private 16-row stripe). LDS 80128 B -> 2 blocks/CU.
__global__ __launch_bounds__(256, 2)
void encode_k(const int* __restrict__ tokens, const void* __restrict__ pad,
              const void* __restrict__ refm, const int* __restrict__ boolflag,
              const float* __restrict__ storage, const float* __restrict__ emb,
              const u16* __restrict__ WqT, const u16* __restrict__ WkT,
              const u16* __restrict__ WvT, const u16* __restrict__ WoT,
              const u16* __restrict__ W1T, const float* __restrict__ b1,
              const u16* __restrict__ W2T, const float* __restrict__ b2,
              const float* __restrict__ ln1s, const float* __restrict__ ln1b,
              const float* __restrict__ ln2s, const float* __restrict__ ln2b,
              const int* __restrict__ sortv, int rank,
              float* __restrict__ outCLS)
{
  const int term = blockIdx.x;
  if (sortv && sortv[term] != rank) return;
  const int flag = *boolflag;

  __shared__ u16 sXb[64 * 256];        // 32 KB bf16 X (swizzled)
  __shared__ u16 sPoolA[64 * 136];     // 17.4 KB: sQK | FFN hidden buf 0
  __shared__ u16 sPoolB[64 * 72 * 3];  // 27 KB: sVT|sO|sP | FFN hidden buf 1
  __shared__ float sStat[64][8];
  __shared__ float sMask[64];

  u16 (*sQK)[136] = (u16(*)[136])sPoolA;
  u16 (*sVT)[72]  = (u16(*)[72])sPoolB;
  u16 (*sO)[72]   = (u16(*)[72])(sPoolB + 64*72);
  u16 (*sP)[72]   = (u16(*)[72])(sPoolB + 2*64*72);
  u16 (*sH0)[136] = (u16(*)[136])sPoolA;
  u16 (*sH1)[136] = (u16(*)[136])sPoolB;

  const int tid = threadIdx.x;
  const int w = tid >> 6, lane = tid & 63, lg = lane >> 4, li = lane & 15;
  const f32x4 zero4 = {0.f, 0.f, 0.f, 0.f};

  if (tid < 64) sMask[tid] = getb(pad, term * 64 + tid, flag) ? 0.f : -1e9f;

  // build X (bf16 into sXb): refmask ? storage[refids] : sum of 3 embeddings
  #pragma unroll 4
  for (int s = 0; s < 64; ++s){
    float v;
    if (getb(refm, term * 64 + s, flag)){
      int rid = tokens[(term * 64 + s) * 3 + 1];
      v = storage[rid * 256 + tid];
    } else {
      int t0 = tokens[(term * 64 + s) * 3 + 0];
      int t1 = tokens[(term * 64 + s) * 3 + 1];
      int t2 = tokens[(term * 64 + s) * 3 + 2];
      v = emb[(0 * 2048 + t0) * 256 + tid]
        + emb[(1 * 2048 + t1) * 256 + tid]
        + emb[(2 * 2048 + t2) * 256 + tid];
    }
    sXb[xoff(s, tid)] = (u16)f2bf(v);
  }
  __syncthreads();

  // X residual in registers at this thread's C-fragment positions
  float xres[4][4][4];
  #pragma unroll
  for (int rt = 0; rt < 4; ++rt)
    #pragma unroll
    for (int ctl = 0; ctl < 4; ++ctl)
      #pragma unroll
      for (int r = 0; r < 4; ++r)
        xres[rt][ctl][r] = bf2f(sXb[xoff(16*rt + 4*lg + r, 64*w + 16*ctl + li)]);

  // A-fragment from swizzled sXb: rows 16rt+li, k-chunk kk (32 elems, 8lg sub)
  auto ldA = [&](int rt, int kk) -> bf16x8 {
    return *(const bf16x8*)&sXb[(16*rt + li) * 256 + (((4*kk + lg) ^ (li & 7)) << 3)];
  };

  for (int l = 0; l < 4; ++l){
    // ================= attention (incremental Wo accumulate) =================
    f32x4 ga[4][4];
    #pragma unroll
    for (int rt = 0; rt < 4; ++rt)
      #pragma unroll
      for (int c = 0; c < 4; ++c) ga[rt][c] = zero4;

    for (int hp = 0; hp < 4; ++hp){   // head pairs
      // ---- QKV GEMM: block-local cols 0..191 = Q(64)|K(64)|V(64); full B hoist
      f32x4 acc[4][3];
      #pragma unroll
      for (int rt = 0; rt < 4; ++rt)
        #pragma unroll
        for (int c = 0; c < 3; ++c) acc[rt][c] = zero4;

      const u16* bptr[3];
      #pragma unroll
      for (int ctl = 0; ctl < 3; ++ctl){
        int c = 48 * w + 16 * ctl;
        int mm = c >> 6;                      // 0:Q 1:K 2:V
        int gcol = hp * 64 + (c & 63) + li;
        const u16* Wt = (mm == 0) ? WqT : ((mm == 1) ? WkT : WvT);
        bptr[ctl] = Wt + ((size_t)(l * 256 + gcol)) * 256 + 8 * lg;
      }
      bf16x8 bq[8][3];
      #pragma unroll
      for (int kt = 0; kt < 8; ++kt)
        #pragma unroll
        for (int ctl = 0; ctl < 3; ++ctl)
          bq[kt][ctl] = *(const bf16x8*)(bptr[ctl] + 32 * kt);
      #pragma unroll
      for (int kt = 0; kt < 8; ++kt){
        bf16x8 a[4];
        #pragma unroll
        for (int rt = 0; rt < 4; ++rt) a[rt] = ldA(rt, kt);
        #pragma unroll
        for (int ctl = 0; ctl < 3; ++ctl)
          #pragma unroll
          for (int rt = 0; rt < 4; ++rt)
            acc[rt][ctl] = __builtin_amdgcn_mfma_f32_16x16x32_bf16(a[rt], bq[kt][ctl], acc[rt][ctl], 0, 0, 0);
      }
      // ---- scatter Q|K to sQK, V^T to sVT (previous hp readers done via sO-complete bar)
      #pragma unroll
      for (int rt = 0; rt < 4; ++rt)
        #pragma unroll
        for (int ctl = 0; ctl < 3; ++ctl){
          int c = 48*w + 16*ctl;
          if (c < 128){
            #pragma unroll
            for (int r = 0; r < 4; ++r)
              sQK[16*rt + 4*lg + r][c + li] = (u16)f2bf(acc[rt][ctl][r]);
          } else {
            s16x4 pk;
            #pragma unroll
            for (int r = 0; r < 4; ++r) pk[r] = f2bf(acc[rt][ctl][r]);
            *(s16x4*)&sVT[c + li - 128][16*rt + 4*lg] = pk;
          }
        }
      __syncthreads();   // post-scatter: sQK/sVT visible to all waves

      // prefetch Wo B-fragments now; latency hides under the whole hh loop
      bf16x8 woB[2][4];
      #pragma unroll
      for (int kt2 = 0; kt2 < 2; ++kt2)
        #pragma unroll
        for (int ctl = 0; ctl < 4; ++ctl)
          woB[kt2][ctl] = *(const bf16x8*)(WoT + ((size_t)(l*256 + 64*w + 16*ctl + li)) * 256
                                           + 64*hp + 32*kt2 + 8*lg);

      #pragma unroll
      for (int hh = 0; hh < 2; ++hh){
        // S = Q K^T / sqrt(HD) + mask ; wave w owns q rows [16w,16w+16)
        bf16x8 aq = *(const bf16x8*)&sQK[16*w + li][32*hh + 8*lg];
        f32x4 sc[4];
        #pragma unroll
        for (int ct = 0; ct < 4; ++ct){
          bf16x8 bk = *(const bf16x8*)&sQK[16*ct + li][64 + 32*hh + 8*lg];
          sc[ct] = __builtin_amdgcn_mfma_f32_16x16x32_bf16(aq, bk, zero4, 0, 0, 0);
        }
        float sv[4][4];
        #pragma unroll
        for (int ct = 0; ct < 4; ++ct){
          float mk = sMask[16*ct + li];
          #pragma unroll
          for (int r = 0; r < 4; ++r) sv[ct][r] = sc[ct][r] * 0.17677669529663687f + mk;
        }
        #pragma unroll
        for (int r = 0; r < 4; ++r){
          float m = fmaxf(fmaxf(sv[0][r], sv[1][r]), fmaxf(sv[2][r], sv[3][r]));
          #pragma unroll
          for (int o = 1; o < 16; o <<= 1) m = fmaxf(m, __shfl_xor(m, o, 64));
          float s0 = 0.f;
          #pragma unroll
          for (int ct = 0; ct < 4; ++ct){ float e = __expf(sv[ct][r] - m); sv[ct][r] = e; s0 += e; }
          #pragma unroll
          for (int o = 1; o < 16; o <<= 1) s0 += __shfl_xor(s0, o, 64);
          float inv = 1.f / s0;
          #pragma unroll
          for (int ct = 0; ct < 4; ++ct) sv[ct][r] *= inv;
        }
        // P stays within this wave's 16-row stripe: NO barriers needed around sP
        #pragma unroll
        for (int ct = 0; ct < 4; ++ct)
          #pragma unroll
          for (int r = 0; r < 4; ++r)
            sP[16*w + 4*lg + r][16*ct + li] = (u16)f2bf(sv[ct][r]);
        // O_h = P @ V_h  (V^T direct b128 reads)
        f32x4 oa[2] = {zero4, zero4};
        #pragma unroll
        for (int kt = 0; kt < 2; ++kt){
          bf16x8 ap = *(const bf16x8*)&sP[16*w + li][32*kt + 8*lg];
          #pragma unroll
          for (int ct = 0; ct < 2; ++ct){
            bf16x8 bv = *(const bf16x8*)&sVT[32*hh + 16*ct + li][32*kt + 8*lg];
            oa[ct] = __builtin_amdgcn_mfma_f32_16x16x32_bf16(ap, bv, oa[ct], 0, 0, 0);
          }
        }
        #pragma unroll
        for (int ct = 0; ct < 2; ++ct)
          #pragma unroll
          for (int r = 0; r < 4; ++r)
            sO[16*w + 4*lg + r][32*hh + 16*ct + li] = (u16)f2bf(oa[ct][r]);
      }
      __syncthreads();   // sO complete (also guards next hp's scatter)
      // partial Wo: ga += O[:, 64hp:64hp+64) @ Wo[64hp:64hp+64, :]
      #pragma unroll
      for (int kt2 = 0; kt2 < 2; ++kt2){
        bf16x8 a[4];
        #pragma unroll
        for (int rt = 0; rt < 4; ++rt)
          a[rt] = *(const bf16x8*)&sO[16*rt + li][32*kt2 + 8*lg];
        #pragma unroll
        for (int ctl = 0; ctl < 4; ++ctl)
          #pragma unroll
          for (int rt = 0; rt < 4; ++rt)
            ga[rt][ctl] = __builtin_amdgcn_mfma_f32_16x16x32_bf16(a[rt], woB[kt2][ctl], ga[rt][ctl], 0, 0, 0);
      }
    } // hp

    // ================= residual + LN1 (regs -> sXb) =================
    {
      float g4[4], bb4[4];
      #pragma unroll
      for (int ctl = 0; ctl < 4; ++ctl){
        int col = 64*w + 16*ctl + li;
        g4[ctl] = ln1s[l*256 + col]; bb4[ctl] = ln1b[l*256 + col];
      }
      float s1v[4][4], s2v[4][4];
      #pragma unroll
      for (int rt = 0; rt < 4; ++rt)
        #pragma unroll
        for (int r = 0; r < 4; ++r){
          float t1 = 0.f, t2 = 0.f;
          #pragma unroll
          for (int ctl = 0; ctl < 4; ++ctl){
            float y = ga[rt][ctl][r] + xres[rt][ctl][r];
            ga[rt][ctl][r] = y; t1 += y; t2 += y * y;
          }
          #pragma unroll
          for (int o = 1; o < 16; o <<= 1){ t1 += __shfl_xor(t1, o, 64); t2 += __shfl_xor(t2, o, 64); }
          s1v[rt][r] = t1; s2v[rt][r] = t2;
        }
      if (li == 0){
        #pragma unroll
        for (int rt = 0; rt < 4; ++rt)
          #pragma unroll
          for (int r = 0; r < 4; ++r){
            sStat[16*rt + 4*lg + r][w] = s1v[rt][r];
            sStat[16*rt + 4*lg + r][4 + w] = s2v[rt][r];
          }
      }
      __syncthreads();
      #pragma unroll
      for (int rt = 0; rt < 4; ++rt)
        #pragma unroll
        for (int r = 0; r < 4; ++r){
          int row = 16*rt + 4*lg + r;
          float su = sStat[row][0] + sStat[row][1] + sStat[row][2] + sStat[row][3];
          float sq = sStat[row][4] + sStat[row][5] + sStat[row][6] + sStat[row][7];
          float mean = su * (1.f / 256.f);
          float var = sq * (1.f / 256.f) - mean * mean;
          float rs = rsqrtf(var + 1e-5f);
          #pragma unroll
          for (int ctl = 0; ctl < 4; ++ctl){
            int col = 64*w + 16*ctl + li;
            float nv = (ga[rt][ctl][r] - mean) * rs * g4[ctl] + bb4[ctl];
            xres[rt][ctl][r] = nv;
            sXb[xoff(row, col)] = (u16)f2bf(nv);
          }
        }
      __syncthreads();
    }

    // ================= FFN: double-buffered hidden, GEMM1(ch+1) || GEMM2(ch) =================
    {
      float b1v[8][2];
      #pragma unroll
      for (int ch = 0; ch < 8; ++ch)
        #pragma unroll
        for (int ctl = 0; ctl < 2; ++ctl)
          b1v[ch][ctl] = b1[l*1024 + 128*ch + 32*w + 16*ctl + li];

      auto ffn1 = [&](int ch, f32x4 (&h)[4][2]){
        #pragma unroll
        for (int rt = 0; rt < 4; ++rt){ h[rt][0] = zero4; h[rt][1] = zero4; }
        const u16* w1p = W1T + ((size_t)(l*1024 + 128*ch + 32*w + li)) * 256 + 8*lg;
        #pragma unroll
        for (int g = 0; g < 2; ++g){
          bf16x8 br[4][2];
          #pragma unroll
          for (int kt = 0; kt < 4; ++kt)
            #pragma unroll
            for (int ctl = 0; ctl < 2; ++ctl)
              br[kt][ctl] = *(const bf16x8*)(w1p + (size_t)ctl*16*256 + 32*(4*g + kt));
          #pragma unroll
          for (int kt = 0; kt < 4; ++kt){
            int kk = 4*g + kt;
            bf16x8 a[4];
            #pragma unroll
            for (int rt = 0; rt < 4; ++rt) a[rt] = ldA(rt, kk);
            #pragma unroll
            for (int ctl = 0; ctl < 2; ++ctl)
              #pragma unroll
              for (int rt = 0; rt < 4; ++rt)
                h[rt][ctl] = __builtin_amdgcn_mfma_f32_16x16x32_bf16(a[rt], br[kt][ctl], h[rt][ctl], 0, 0, 0);
          }
        }
      };

      f32x4 fa[4][4];
      #pragma unroll
      for (int rt = 0; rt < 4; ++rt)
        #pragma unroll
        for (int c = 0; c < 4; ++c) fa[rt][c] = zero4;

      f32x4 ha[4][2];
      ffn1(0, ha);
      for (int ch = 0; ch < 8; ++ch){
        u16 (*sHc)[136] = (ch & 1) ? sH1 : sH0;
        #pragma unroll
        for (int rt = 0; rt < 4; ++rt)
          #pragma unroll
          for (int ctl = 0; ctl < 2; ++ctl)
            #pragma unroll
            for (int r = 0; r < 4; ++r){
              float v = ha[rt][ctl][r] + b1v[ch][ctl];
              sHc[16*rt + 4*lg + r][32*w + 16*ctl + li] = (u16)f2bf(fmaxf(v, 0.f));
            }
        __syncthreads();    // hidden chunk visible; prev chunk's readers done (other buffer)
        f32x4 hb[4][2];
        if (ch < 7) ffn1(ch + 1, hb);
        // GEMM2(ch): fa += relu(H_ch) @ W2[128ch:128ch+128, :]
        const u16* w2p = W2T + ((size_t)(l*256 + 64*w + li)) * 1024 + 128*ch + 8*lg;
        #pragma unroll
        for (int g = 0; g < 2; ++g){
          bf16x8 br[2][4];
          #pragma unroll
          for (int kt = 0; kt < 2; ++kt)
            #pragma unroll
            for (int ctl = 0; ctl < 4; ++ctl)
              br[kt][ctl] = *(const bf16x8*)(w2p + (size_t)ctl*16*1024 + 32*(2*g + kt));
          #pragma unroll
          for (int kt = 0; kt < 2; ++kt){
            int kk = 2*g + kt;
            bf16x8 a[4];
            #pragma unroll
            for (int rt = 0; rt < 4; ++rt)
              a[rt] = *(const bf16x8*)&sHc[16*rt + li][32*kk + 8*lg];
            #pragma unroll
            for (int ctl = 0; ctl < 4; ++ctl)
              #pragma unroll
              for (int rt = 0; rt < 4; ++rt)
                fa[rt][ctl] = __builtin_amdgcn_mfma_f32_16x16x32_bf16(a[rt], br[kt][ctl], fa[rt][ctl], 0, 0, 0);
          }
        }
        if (ch < 7){
          #pragma unroll
          for (int rt = 0; rt < 4; ++rt)
            #pragma unroll
            for (int ctl = 0; ctl < 2; ++ctl)
              ha[rt][ctl] = hb[rt][ctl];
        }
      }

      // ---- residual + bias + LN2
      float g4[4], bb4[4], b2v[4];
      #pragma unroll
      for (int ctl = 0; ctl < 4; ++ctl){
        int col = 64*w + 16*ctl + li;
        g4[ctl] = ln2s[l*256 + col]; bb4[ctl] = ln2b[l*256 + col]; b2v[ctl] = b2[l*256 + col];
      }
      float s1v[4][4], s2v[4][4];
      #pragma unroll
      for (int rt = 0; rt < 4; ++rt)
        #pragma unroll
        for (int r = 0; r < 4; ++r){
          float t1 = 0.f, t2 = 0.f;
          #pragma unroll
          for (int ctl = 0; ctl < 4; ++ctl){
            float y = fa[rt][ctl][r] + xres[rt][ctl][r] + b2v[ctl];
            fa[rt][ctl][r] = y; t1 += y; t2 += y * y;
          }
          #pragma unroll
          for (int o = 1; o < 16; o <<= 1){ t1 += __shfl_xor(t1, o, 64); t2 += __shfl_xor(t2, o, 64); }
          s1v[rt][r] = t1; s2v[rt][r] = t2;
        }
      if (li == 0){
        #pragma unroll
        for (int rt = 0; rt < 4; ++rt)
          #pragma unroll
          for (int r = 0; r < 4; ++r){
            sStat[16*rt + 4*lg + r][w] = s1v[rt][r];
            sStat[16*rt + 4*lg + r][4 + w] = s2v[rt][r];
          }
      }
      __syncthreads();
      #pragma unroll
      for (int rt = 0; rt < 4; ++rt)
        #pragma unroll
        for (int r = 0; r < 4; ++r){
          int row = 16*rt + 4*lg + r;
          float su = sStat[row][0] + sStat[row][1] + sStat[row][2] + sStat[row][3];
          float sq = sStat[row][4] + sStat[row][5] + sStat[row][6] + sStat[row][7];
          float mean = su * (1.f / 256.f);
          float var = sq * (1.f / 256.f) - mean * mean;
          float rs = rsqrtf(var + 1e-5f);
          #pragma unroll
          for (int ctl = 0; ctl < 4; ++ctl){
            int col = 64*w + 16*ctl + li;
            float nv = (fa[rt][ctl][r] - mean) * rs * g4[ctl] + bb4[ctl];
            xres[rt][ctl][r] = nv;
            sXb[xoff(row, col)] = (u16)f2bf(nv);
            if (l == 3 && outCLS && row == 0) outCLS[term * 256 + col] = nv;
          }
        }
      __syncthreads();
    }
  }
}

extern "C" void kernel_launch(void* const* d_in, const int* in_sizes, int n_in,
                              void* d_out, int out_size, void* d_ws, size_t ws_size,
                              hipStream_t stream)
{
  (void)in_sizes; (void)n_in; (void)out_size; (void)ws_size;
  const int* tokens_scope = (const int*)d_in[0];
  const int* tokens_hole  = (const int*)d_in[1];
  const void* pad_scope = d_in[2];
  const void* pad_hole  = d_in[3];
  const void* ref_scope = d_in[4];
  const void* ref_hole  = d_in[5];
  const int* scope_sort = (const int*)d_in[6];
  const int* scope_pos  = (const int*)d_in[7];
  const float* emb  = (const float*)d_in[8];
  const float* Wq   = (const float*)d_in[9];
  const float* Wk   = (const float*)d_in[10];
  const float* Wv   = (const float*)d_in[11];
  const float* Wo   = (const float*)d_in[12];
  const float* ln1s = (const float*)d_in[13];
  const float* ln1b = (const float*)d_in[14];
  const float* W1   = (const float*)d_in[15];
  const float* b1   = (const float*)d_in[16];
  const float* W2   = (const float*)d_in[17];
  const float* b2   = (const float*)d_in[18];
  const float* ln2s = (const float*)d_in[19];
  const float* ln2b = (const float*)d_in[20];

  char* p = (char*)d_ws;
  float* reprs  = (float*)p; p += (size_t)2048*256*4;
  float* encCLS = (float*)p; p += (size_t)2048*256*4;
  u16* WqT = (u16*)p; p += (size_t)4*256*256*2;
  u16* WkT = (u16*)p; p += (size_t)4*256*256*2;
  u16* WvT = (u16*)p; p += (size_t)4*256*256*2;
  u16* WoT = (u16*)p; p += (size_t)4*256*256*2;
  u16* W1T = (u16*)p; p += (size_t)4*256*1024*2;
  u16* W2T = (u16*)p; p += (size_t)4*256*1024*2;
  int* flag = (int*)p; p += 16;

  hipLaunchKernelGGL(detect_bool_k, dim3(1), dim3(1), 0, stream, pad_scope, flag);
  hipLaunchKernelGGL(transpose_k, dim3(1024), dim3(256), 0, stream, Wq, WqT, 256, 256);
  hipLaunchKernelGGL(transpose_k, dim3(1024), dim3(256), 0, stream, Wk, WkT, 256, 256);
  hipLaunchKernelGGL(transpose_k, dim3(1024), dim3(256), 0, stream, Wv, WvT, 256, 256);
  hipLaunchKernelGGL(transpose_k, dim3(1024), dim3(256), 0, stream, Wo, WoT, 256, 256);
  hipLaunchKernelGGL(transpose_k, dim3(4096), dim3(256), 0, stream, W1, W1T, 256, 1024);
  hipLaunchKernelGGL(transpose_k, dim3(4096), dim3(256), 0, stream, W2, W2T, 1024, 256);
  hipLaunchKernelGGL(pos_init_k, dim3(2048), dim3(256), 0, stream, scope_pos, reprs);

  for (int r = 0; r < 4; ++r){
    hipLaunchKernelGGL(encode_k, dim3(2048), dim3(256), 0, stream,
      tokens_scope, pad_scope, ref_scope, flag, reprs, emb,
      WqT, WkT, WvT, WoT, W1T, b1, W2T, b2, ln1s, ln1b, ln2s, ln2b,
      scope_sort, r, encCLS);
    hipLaunchKernelGGL(update_k, dim3(2048), dim3(256), 0, stream, scope_sort, encCLS, reprs, r);
  }
  hipLaunchKernelGGL(encode_k, dim3(512), dim3(256), 0, stream,
      tokens_hole, pad_hole, ref_hole, flag, reprs, emb,
      WqT, WkT, WvT, WoT, W1T, b1, W2T, b2, ln1s, ln1b, ln2s, ln2b,
      (const int*)nullptr, 0, (float*)d_out + (size_t)2048*256);
  hipLaunchKernelGGL(writeout_k, dim3(2048), dim3(256), 0, stream, reprs, (float*)d_out);
}

// Round 5
// 4994.035 us; speedup vs baseline: 1.6730x; 1.0573x over previous
//
#include <hip/hip_runtime.h>
#include <stdint.h>
#include <math.h>

typedef __attribute__((ext_vector_type(8))) short bf16x8;
typedef __attribute__((ext_vector_type(4))) short s16x4;
typedef __attribute__((ext_vector_type(4))) float f32x4;
typedef unsigned short u16;

// raw barrier: LDS drain only; global (vmcnt) prefetches stay in flight
#define SBAR() asm volatile("s_waitcnt lgkmcnt(0)\ns_barrier" ::: "memory")

__device__ __forceinline__ short f2bf(float f){
  union { float f; uint32_t u; } v; v.f = f;
  uint32_t r = v.u + 0x7FFFu + ((v.u >> 16) & 1u);
  return (short)(r >> 16);
}
__device__ __forceinline__ float bf2f(u16 b){
  union { uint32_t u; float f; } v; v.u = ((uint32_t)b) << 16; return v.f;
}
// bool inputs may arrive as uint8 (numpy bool) or int32; runtime-detected flag selects.
__device__ __forceinline__ bool getb(const void* p, int i, int flag){
  if (flag) return ((const unsigned char*)p)[i] != 0;
  return ((const int*)p)[i] != 0;
}
// XOR-swizzled offset into the bf16 X buffer [64 rows][256 cols]
__device__ __forceinline__ int xoff(int row, int col){
  int g = (col >> 3) ^ (row & 7);
  return row * 256 + (g << 3) + (col & 7);
}

__global__ void detect_bool_k(const void* pad, int* flag){
  const unsigned char* b = (const unsigned char*)pad;
  int f = 0;
  for (int i = 1; i < 64; ++i) if (i & 3) f |= (b[i] != 0) ? 1 : 0;
  *flag = f;
}

__global__ void transpose_k(const float* __restrict__ src, u16* __restrict__ dst, int R, int C){
  // src f32 [mats][R][C] -> dst bf16 [mats][C][R]; grid*256 == mats*R*C exactly
  long idx = (long)blockIdx.x * blockDim.x + threadIdx.x;
  int r = (int)(idx % R);
  long t = idx / R;
  int c = (int)(t % C);
  int m = (int)(t / C);
  dst[idx] = (u16)f2bf(src[((long)m * R + r) * C + c]);
}

__global__ void emb2bf_k(const float* __restrict__ src, u16* __restrict__ dst){
  long i = (long)blockIdx.x * blockDim.x + threadIdx.x;
  dst[i] = (u16)f2bf(src[i]);
}

__global__ void pos_init_k(const int* __restrict__ pos, float* __restrict__ reprs){
  int n = blockIdx.x, d = threadIdx.x;
  double p = (double)pos[n];
  int i = (d < 128) ? d : d - 128;
  double ang = p / pow(500.0, (2.0 * (double)i) / 256.0);
  reprs[n * 256 + d] = (d < 128) ? (float)sin(ang) : (float)cos(ang);
}

__global__ void update_k(const int* __restrict__ sortv, const float* __restrict__ encCLS,
                         float* __restrict__ reprs, int rank){
  int t = blockIdx.x;
  if (sortv[t] != rank) return;
  reprs[t * 256 + threadIdx.x] += encCLS[t * 256 + threadIdx.x];
}

__global__ void writeout_k(const float* __restrict__ reprs, float* __restrict__ out){
  int i = blockIdx.x * 256 + threadIdx.x;
  out[i] = reprs[i];
}

// One block = one term, 4 waves, all 4 layers fused.
// X residual in registers; bf16 X (XOR-swizzled) in LDS; raw lgkm-only barriers so
// global weight prefetches stay in flight across sync points.
__global__ __launch_bounds__(256, 2)
void encode_k(const int* __restrict__ tokens, const void* __restrict__ pad,
              const void* __restrict__ refm, const int* __restrict__ boolflag,
              const float* __restrict__ storage, const u16* __restrict__ embB,
              const u16* __restrict__ WqT, const u16* __restrict__ WkT,
              const u16* __restrict__ WvT, const u16* __restrict__ WoT,
              const u16* __restrict__ W1T, const float* __restrict__ b1,
              const u16* __restrict__ W2T, const float* __restrict__ b2,
              const float* __restrict__ ln1s, const float* __restrict__ ln1b,
              const float* __restrict__ ln2s, const float* __restrict__ ln2b,
              const int* __restrict__ sortv, int rank,
              float* __restrict__ outCLS)
{
  const int term = blockIdx.x;
  if (sortv && sortv[term] != rank) return;
  const int flag = *boolflag;

  __shared__ u16 sXb[64 * 256];        // 32 KB bf16 X (swizzled)
  __shared__ u16 sPoolA[64 * 136];     // sQK | FFN hidden buf 0
  __shared__ u16 sPoolB[64 * 72 * 3];  // sVT|sO|sP | FFN hidden buf 1
  __shared__ float sStat[64][8];
  __shared__ float sMask[64];
  __shared__ int sTok[192];
  __shared__ int sRef[64];

  u16 (*sQK)[136] = (u16(*)[136])sPoolA;
  u16 (*sVT)[72]  = (u16(*)[72])sPoolB;
  u16 (*sO)[72]   = (u16(*)[72])(sPoolB + 64*72);
  u16 (*sP)[72]   = (u16(*)[72])(sPoolB + 2*64*72);
  u16 (*sH0)[136] = (u16(*)[136])sPoolA;
  u16 (*sH1)[136] = (u16(*)[136])sPoolB;

  const int tid = threadIdx.x;
  const int w = tid >> 6, lane = tid & 63, lg = lane >> 4, li = lane & 15;
  const f32x4 zero4 = {0.f, 0.f, 0.f, 0.f};

  // stage token ids + masks in LDS (kills the serial dependent-load chain)
  if (tid < 192) sTok[tid] = tokens[term * 192 + tid];
  if (tid < 64){
    sMask[tid] = getb(pad, term * 64 + tid, flag) ? 0.f : -1e9f;
    sRef[tid] = getb(refm, term * 64 + tid, flag) ? 1 : 0;
  }
  SBAR();

  // build X (bf16 into sXb): refmask ? storage[refids] : sum of 3 embeddings
  #pragma unroll 4
  for (int s = 0; s < 64; ++s){
    float v;
    if (sRef[s]){
      v = storage[sTok[3*s + 1] * 256 + tid];
    } else {
      v = bf2f(embB[sTok[3*s + 0] * 256 + tid])
        + bf2f(embB[(2048 + sTok[3*s + 1]) * 256 + tid])
        + bf2f(embB[(4096 + sTok[3*s + 2]) * 256 + tid]);
    }
    sXb[xoff(s, tid)] = (u16)f2bf(v);
  }
  SBAR();

  // X residual in registers at this thread's C-fragment positions
  float xres[4][4][4];
  #pragma unroll
  for (int rt = 0; rt < 4; ++rt)
    #pragma unroll
    for (int ctl = 0; ctl < 4; ++ctl)
      #pragma unroll
      for (int r = 0; r < 4; ++r)
        xres[rt][ctl][r] = bf2f(sXb[xoff(16*rt + 4*lg + r, 64*w + 16*ctl + li)]);

  // A-fragment from swizzled sXb
  auto ldA = [&](int rt, int kk) -> bf16x8 {
    return *(const bf16x8*)&sXb[(16*rt + li) * 256 + (((4*kk + lg) ^ (li & 7)) << 3)];
  };

  for (int l = 0; l < 4; ++l){
    // ================= attention (incremental Wo accumulate) =================
    f32x4 ga[4][4];
    #pragma unroll
    for (int rt = 0; rt < 4; ++rt)
      #pragma unroll
      for (int c = 0; c < 4; ++c) ga[rt][c] = zero4;

    for (int hp = 0; hp < 4; ++hp){
      // ---- QKV GEMM
      f32x4 acc[4][3];
      #pragma unroll
      for (int rt = 0; rt < 4; ++rt)
        #pragma unroll
        for (int c = 0; c < 3; ++c) acc[rt][c] = zero4;

      const u16* bptr[3];
      #pragma unroll
      for (int ctl = 0; ctl < 3; ++ctl){
        int c = 48 * w + 16 * ctl;
        int mm = c >> 6;                      // 0:Q 1:K 2:V
        int gcol = hp * 64 + (c & 63) + li;
        const u16* Wt = (mm == 0) ? WqT : ((mm == 1) ? WkT : WvT);
        bptr[ctl] = Wt + ((size_t)(l * 256 + gcol)) * 256 + 8 * lg;
      }
      bf16x8 bq[8][3];
      #pragma unroll
      for (int kt = 0; kt < 8; ++kt)
        #pragma unroll
        for (int ctl = 0; ctl < 3; ++ctl)
          bq[kt][ctl] = *(const bf16x8*)(bptr[ctl] + 32 * kt);
      #pragma unroll
      for (int kt = 0; kt < 8; ++kt){
        bf16x8 a[4];
        #pragma unroll
        for (int rt = 0; rt < 4; ++rt) a[rt] = ldA(rt, kt);
        #pragma unroll
        for (int ctl = 0; ctl < 3; ++ctl)
          #pragma unroll
          for (int rt = 0; rt < 4; ++rt)
            acc[rt][ctl] = __builtin_amdgcn_mfma_f32_16x16x32_bf16(a[rt], bq[kt][ctl], acc[rt][ctl], 0, 0, 0);
      }
      // ---- scatter Q|K to sQK, V^T to sVT
      #pragma unroll
      for (int rt = 0; rt < 4; ++rt)
        #pragma unroll
        for (int ctl = 0; ctl < 3; ++ctl){
          int c = 48*w + 16*ctl;
          if (c < 128){
            #pragma unroll
            for (int r = 0; r < 4; ++r)
              sQK[16*rt + 4*lg + r][c + li] = (u16)f2bf(acc[rt][ctl][r]);
          } else {
            s16x4 pk;
            #pragma unroll
            for (int r = 0; r < 4; ++r) pk[r] = f2bf(acc[rt][ctl][r]);
            *(s16x4*)&sVT[c + li - 128][16*rt + 4*lg] = pk;
          }
        }
      // prefetch Wo B-fragments BEFORE the barrier (raw barrier keeps them in flight;
      // consumed after the hh loop -> latency fully hidden)
      bf16x8 woB[2][4];
      #pragma unroll
      for (int kt2 = 0; kt2 < 2; ++kt2)
        #pragma unroll
        for (int ctl = 0; ctl < 4; ++ctl)
          woB[kt2][ctl] = *(const bf16x8*)(WoT + ((size_t)(l*256 + 64*w + 16*ctl + li)) * 256
                                           + 64*hp + 32*kt2 + 8*lg);
      SBAR();   // post-scatter: sQK/sVT visible

      #pragma unroll
      for (int hh = 0; hh < 2; ++hh){
        bf16x8 aq = *(const bf16x8*)&sQK[16*w + li][32*hh + 8*lg];
        f32x4 sc[4];
        #pragma unroll
        for (int ct = 0; ct < 4; ++ct){
          bf16x8 bk = *(const bf16x8*)&sQK[16*ct + li][64 + 32*hh + 8*lg];
          sc[ct] = __builtin_amdgcn_mfma_f32_16x16x32_bf16(aq, bk, zero4, 0, 0, 0);
        }
        float sv[4][4];
        #pragma unroll
        for (int ct = 0; ct < 4; ++ct){
          float mk = sMask[16*ct + li];
          #pragma unroll
          for (int r = 0; r < 4; ++r) sv[ct][r] = sc[ct][r] * 0.17677669529663687f + mk;
        }
        #pragma unroll
        for (int r = 0; r < 4; ++r){
          float m = fmaxf(fmaxf(sv[0][r], sv[1][r]), fmaxf(sv[2][r], sv[3][r]));
          #pragma unroll
          for (int o = 1; o < 16; o <<= 1) m = fmaxf(m, __shfl_xor(m, o, 64));
          float s0 = 0.f;
          #pragma unroll
          for (int ct = 0; ct < 4; ++ct){ float e = __expf(sv[ct][r] - m); sv[ct][r] = e; s0 += e; }
          #pragma unroll
          for (int o = 1; o < 16; o <<= 1) s0 += __shfl_xor(s0, o, 64);
          float inv = 1.f / s0;
          #pragma unroll
          for (int ct = 0; ct < 4; ++ct) sv[ct][r] *= inv;
        }
        // P wave-private (16-row stripe): no barriers around sP
        #pragma unroll
        for (int ct = 0; ct < 4; ++ct)
          #pragma unroll
          for (int r = 0; r < 4; ++r)
            sP[16*w + 4*lg + r][16*ct + li] = (u16)f2bf(sv[ct][r]);
        f32x4 oa[2] = {zero4, zero4};
        #pragma unroll
        for (int kt = 0; kt < 2; ++kt){
          bf16x8 ap = *(const bf16x8*)&sP[16*w + li][32*kt + 8*lg];
          #pragma unroll
          for (int ct = 0; ct < 2; ++ct){
            bf16x8 bv = *(const bf16x8*)&sVT[32*hh + 16*ct + li][32*kt + 8*lg];
            oa[ct] = __builtin_amdgcn_mfma_f32_16x16x32_bf16(ap, bv, oa[ct], 0, 0, 0);
          }
        }
        #pragma unroll
        for (int ct = 0; ct < 2; ++ct)
          #pragma unroll
          for (int r = 0; r < 4; ++r)
            sO[16*w + 4*lg + r][32*hh + 16*ct + li] = (u16)f2bf(oa[ct][r]);
      }
      SBAR();   // sO complete (also guards next hp's scatter)
      // partial Wo: ga += O[:, 64hp:64hp+64) @ Wo[64hp:64hp+64, :]  (woB already resident)
      #pragma unroll
      for (int kt2 = 0; kt2 < 2; ++kt2){
        bf16x8 a[4];
        #pragma unroll
        for (int rt = 0; rt < 4; ++rt)
          a[rt] = *(const bf16x8*)&sO[16*rt + li][32*kt2 + 8*lg];
        #pragma unroll
        for (int ctl = 0; ctl < 4; ++ctl)
          #pragma unroll
          for (int rt = 0; rt < 4; ++rt)
            ga[rt][ctl] = __builtin_amdgcn_mfma_f32_16x16x32_bf16(a[rt], woB[kt2][ctl], ga[rt][ctl], 0, 0, 0);
      }
    } // hp

    // ================= residual + LN1 (regs -> sXb) =================
    {
      float g4[4], bb4[4];
      #pragma unroll
      for (int ctl = 0; ctl < 4; ++ctl){
        int col = 64*w + 16*ctl + li;
        g4[ctl] = ln1s[l*256 + col]; bb4[ctl] = ln1b[l*256 + col];
      }
      float s1v[4][4], s2v[4][4];
      #pragma unroll
      for (int rt = 0; rt < 4; ++rt)
        #pragma unroll
        for (int r = 0; r < 4; ++r){
          float t1 = 0.f, t2 = 0.f;
          #pragma unroll
          for (int ctl = 0; ctl < 4; ++ctl){
            float y = ga[rt][ctl][r] + xres[rt][ctl][r];
            ga[rt][ctl][r] = y; t1 += y; t2 += y * y;
          }
          #pragma unroll
          for (int o = 1; o < 16; o <<= 1){ t1 += __shfl_xor(t1, o, 64); t2 += __shfl_xor(t2, o, 64); }
          s1v[rt][r] = t1; s2v[rt][r] = t2;
        }
      if (li == 0){
        #pragma unroll
        for (int rt = 0; rt < 4; ++rt)
          #pragma unroll
          for (int r = 0; r < 4; ++r){
            sStat[16*rt + 4*lg + r][w] = s1v[rt][r];
            sStat[16*rt + 4*lg + r][4 + w] = s2v[rt][r];
          }
      }
      SBAR();
      #pragma unroll
      for (int rt = 0; rt < 4; ++rt)
        #pragma unroll
        for (int r = 0; r < 4; ++r){
          int row = 16*rt + 4*lg + r;
          float su = sStat[row][0] + sStat[row][1] + sStat[row][2] + sStat[row][3];
          float sq = sStat[row][4] + sStat[row][5] + sStat[row][6] + sStat[row][7];
          float mean = su * (1.f / 256.f);
          float var = sq * (1.f / 256.f) - mean * mean;
          float rs = rsqrtf(var + 1e-5f);
          #pragma unroll
          for (int ctl = 0; ctl < 4; ++ctl){
            int col = 64*w + 16*ctl + li;
            float nv = (ga[rt][ctl][r] - mean) * rs * g4[ctl] + bb4[ctl];
            xres[rt][ctl][r] = nv;
            sXb[xoff(row, col)] = (u16)f2bf(nv);
          }
        }
      SBAR();
    }

    // ================= FFN: double-buffered hidden, pipelined W loads =================
    {
      float b1v[8][2];
      #pragma unroll
      for (int ch = 0; ch < 8; ++ch)
        #pragma unroll
        for (int ctl = 0; ctl < 2; ++ctl)
          b1v[ch][ctl] = b1[l*1024 + 128*ch + 32*w + 16*ctl + li];

      bf16x8 w1f[2][8];
      auto loadW1 = [&](int ch){
        const u16* w1p = W1T + ((size_t)(l*1024 + 128*ch + 32*w + li)) * 256 + 8*lg;
        #pragma unroll
        for (int ctl = 0; ctl < 2; ++ctl)
          #pragma unroll
          for (int kt = 0; kt < 8; ++kt)
            w1f[ctl][kt] = *(const bf16x8*)(w1p + (size_t)ctl*16*256 + 32*kt);
      };
      auto mfma1 = [&](f32x4 (*h)[2]){
        #pragma unroll
        for (int rt = 0; rt < 4; ++rt){ h[rt][0] = zero4; h[rt][1] = zero4; }
        #pragma unroll
        for (int kt = 0; kt < 8; ++kt){
          bf16x8 a[4];
          #pragma unroll
          for (int rt = 0; rt < 4; ++rt) a[rt] = ldA(rt, kt);
          #pragma unroll
          for (int ctl = 0; ctl < 2; ++ctl)
            #pragma unroll
            for (int rt = 0; rt < 4; ++rt)
              h[rt][ctl] = __builtin_amdgcn_mfma_f32_16x16x32_bf16(a[rt], w1f[ctl][kt], h[rt][ctl], 0, 0, 0);
        }
      };

      f32x4 fa[4][4];
      #pragma unroll
      for (int rt = 0; rt < 4; ++rt)
        #pragma unroll
        for (int c = 0; c < 4; ++c) fa[rt][c] = zero4;

      f32x4 haA[4][2], haB[4][2];
      loadW1(0);
      mfma1(haA);

      #pragma unroll
      for (int ch = 0; ch < 8; ++ch){
        f32x4 (*cur)[2] = (ch & 1) ? haB : haA;
        f32x4 (*nxt)[2] = (ch & 1) ? haA : haB;
        u16 (*sHc)[136] = (ch & 1) ? sH1 : sH0;
        #pragma unroll
        for (int rt = 0; rt < 4; ++rt)
          #pragma unroll
          for (int ctl = 0; ctl < 2; ++ctl)
            #pragma unroll
            for (int r = 0; r < 4; ++r){
              float v = cur[rt][ctl][r] + b1v[ch][ctl];
              sHc[16*rt + 4*lg + r][32*w + 16*ctl + li] = (u16)f2bf(fmaxf(v, 0.f));
            }
        // pre-barrier issue of W2(ch) first half; survives the raw barrier
        const u16* w2p = W2T + ((size_t)(l*256 + 64*w + li)) * 1024 + 128*ch + 8*lg;
        bf16x8 w2a[2][4];
        #pragma unroll
        for (int kt = 0; kt < 2; ++kt)
          #pragma unroll
          for (int ctl = 0; ctl < 4; ++ctl)
            w2a[kt][ctl] = *(const bf16x8*)(w2p + (size_t)ctl*16*1024 + 32*kt);
        SBAR();    // hidden chunk visible
        if (ch < 7) loadW1(ch + 1);   // issue next GEMM1 weights; hidden under GEMM2
        // GEMM2(ch) first half (w2a resident)
        #pragma unroll
        for (int kt = 0; kt < 2; ++kt){
          bf16x8 a[4];
          #pragma unroll
          for (int rt = 0; rt < 4; ++rt)
            a[rt] = *(const bf16x8*)&sHc[16*rt + li][32*kt + 8*lg];
          #pragma unroll
          for (int ctl = 0; ctl < 4; ++ctl)
            #pragma unroll
            for (int rt = 0; rt < 4; ++rt)
              fa[rt][ctl] = __builtin_amdgcn_mfma_f32_16x16x32_bf16(a[rt], w2a[kt][ctl], fa[rt][ctl], 0, 0, 0);
        }
        // GEMM2(ch) second half (loads inline)
        #pragma unroll
        for (int kt = 2; kt < 4; ++kt){
          bf16x8 br[4];
          #pragma unroll
          for (int ctl = 0; ctl < 4; ++ctl)
            br[ctl] = *(const bf16x8*)(w2p + (size_t)ctl*16*1024 + 32*kt);
          bf16x8 a[4];
          #pragma unroll
          for (int rt = 0; rt < 4; ++rt)
            a[rt] = *(const bf16x8*)&sHc[16*rt + li][32*kt + 8*lg];
          #pragma unroll
          for (int ctl = 0; ctl < 4; ++ctl)
            #pragma unroll
            for (int rt = 0; rt < 4; ++rt)
              fa[rt][ctl] = __builtin_amdgcn_mfma_f32_16x16x32_bf16(a[rt], br[ctl], fa[rt][ctl], 0, 0, 0);
        }
        if (ch < 7) mfma1(nxt);   // W1 arrived during GEMM2
      }

      // ---- residual + bias + LN2
      float g4[4], bb4[4], b2v[4];
      #pragma unroll
      for (int ctl = 0; ctl < 4; ++ctl){
        int col = 64*w + 16*ctl + li;
        g4[ctl] = ln2s[l*256 + col]; bb4[ctl] = ln2b[l*256 + col]; b2v[ctl] = b2[l*256 + col];
      }
      float s1v[4][4], s2v[4][4];
      #pragma unroll
      for (int rt = 0; rt < 4; ++rt)
        #pragma unroll
        for (int r = 0; r < 4; ++r){
          float t1 = 0.f, t2 = 0.f;
          #pragma unroll
          for (int ctl = 0; ctl < 4; ++ctl){
            float y = fa[rt][ctl][r] + xres[rt][ctl][r] + b2v[ctl];
            fa[rt][ctl][r] = y; t1 += y; t2 += y * y;
          }
          #pragma unroll
          for (int o = 1; o < 16; o <<= 1){ t1 += __shfl_xor(t1, o, 64); t2 += __shfl_xor(t2, o, 64); }
          s1v[rt][r] = t1; s2v[rt][r] = t2;
        }
      if (li == 0){
        #pragma unroll
        for (int rt = 0; rt < 4; ++rt)
          #pragma unroll
          for (int r = 0; r < 4; ++r){
            sStat[16*rt + 4*lg + r][w] = s1v[rt][r];
            sStat[16*rt + 4*lg + r][4 + w] = s2v[rt][r];
          }
      }
      SBAR();
      #pragma unroll
      for (int rt = 0; rt < 4; ++rt)
        #pragma unroll
        for (int r = 0; r < 4; ++r){
          int row = 16*rt + 4*lg + r;
          float su = sStat[row][0] + sStat[row][1] + sStat[row][2] + sStat[row][3];
          float sq = sStat[row][4] + sStat[row][5] + sStat[row][6] + sStat[row][7];
          float mean = su * (1.f / 256.f);
          float var = sq * (1.f / 256.f) - mean * mean;
          float rs = rsqrtf(var + 1e-5f);
          #pragma unroll
          for (int ctl = 0; ctl < 4; ++ctl){
            int col = 64*w + 16*ctl + li;
            float nv = (fa[rt][ctl][r] - mean) * rs * g4[ctl] + bb4[ctl];
            xres[rt][ctl][r] = nv;
            sXb[xoff(row, col)] = (u16)f2bf(nv);
            if (l == 3 && outCLS && row == 0) outCLS[term * 256 + col] = nv;
          }
        }
      SBAR();
    }
  }
}

extern "C" void kernel_launch(void* const* d_in, const int* in_sizes, int n_in,
                              void* d_out, int out_size, void* d_ws, size_t ws_size,
                              hipStream_t stream)
{
  (void)in_sizes; (void)n_in; (void)out_size; (void)ws_size;
  const int* tokens_scope = (const int*)d_in[0];
  const int* tokens_hole  = (const int*)d_in[1];
  const void* pad_scope = d_in[2];
  const void* pad_hole  = d_in[3];
  const void* ref_scope = d_in[4];
  const void* ref_hole  = d_in[5];
  const int* scope_sort = (const int*)d_in[6];
  const int* scope_pos  = (const int*)d_in[7];
  const float* emb  = (const float*)d_in[8];
  const float* Wq   = (const float*)d_in[9];
  const float* Wk   = (const float*)d_in[10];
  const float* Wv   = (const float*)d_in[11];
  const float* Wo   = (const float*)d_in[12];
  const float* ln1s = (const float*)d_in[13];
  const float* ln1b = (const float*)d_in[14];
  const float* W1   = (const float*)d_in[15];
  const float* b1   = (const float*)d_in[16];
  const float* W2   = (const float*)d_in[17];
  const float* b2   = (const float*)d_in[18];
  const float* ln2s = (const float*)d_in[19];
  const float* ln2b = (const float*)d_in[20];

  char* p = (char*)d_ws;
  float* reprs  = (float*)p; p += (size_t)2048*256*4;
  float* encCLS = (float*)p; p += (size_t)2048*256*4;
  u16* WqT = (u16*)p; p += (size_t)4*256*256*2;
  u16* WkT = (u16*)p; p += (size_t)4*256*256*2;
  u16* WvT = (u16*)p; p += (size_t)4*256*256*2;
  u16* WoT = (u16*)p; p += (size_t)4*256*256*2;
  u16* W1T = (u16*)p; p += (size_t)4*256*1024*2;
  u16* W2T = (u16*)p; p += (size_t)4*256*1024*2;
  u16* embB = (u16*)p; p += (size_t)3*2048*256*2;
  int* flag = (int*)p; p += 16;

  hipLaunchKernelGGL(detect_bool_k, dim3(1), dim3(1), 0, stream, pad_scope, flag);
  hipLaunchKernelGGL(emb2bf_k, dim3(6144), dim3(256), 0, stream, emb, embB);
  hipLaunchKernelGGL(transpose_k, dim3(1024), dim3(256), 0, stream, Wq, WqT, 256, 256);
  hipLaunchKernelGGL(transpose_k, dim3(1024), dim3(256), 0, stream, Wk, WkT, 256, 256);
  hipLaunchKernelGGL(transpose_k, dim3(1024), dim3(256), 0, stream, Wv, WvT, 256, 256);
  hipLaunchKernelGGL(transpose_k, dim3(1024), dim3(256), 0, stream, Wo, WoT, 256, 256);
  hipLaunchKernelGGL(transpose_k, dim3(4096), dim3(256), 0, stream, W1, W1T, 256, 1024);
  hipLaunchKernelGGL(transpose_k, dim3(4096), dim3(256), 0, stream, W2, W2T, 1024, 256);
  hipLaunchKernelGGL(pos_init_k, dim3(2048), dim3(256), 0, stream, scope_pos, reprs);

  for (int r = 0; r < 4; ++r){
    hipLaunchKernelGGL(encode_k, dim3(2048), dim3(256), 0, stream,
      tokens_scope, pad_scope, ref_scope, flag, reprs, embB,
      WqT, WkT, WvT, WoT, W1T, b1, W2T, b2, ln1s, ln1b, ln2s, ln2b,
      scope_sort, r, encCLS);
    hipLaunchKernelGGL(update_k, dim3(2048), dim3(256), 0, stream, scope_sort, encCLS, reprs, r);
  }
  hipLaunchKernelGGL(encode_k, dim3(512), dim3(256), 0, stream,
      tokens_hole, pad_hole, ref_hole, flag, reprs, embB,
      WqT, WkT, WvT, WoT, W1T, b1, W2T, b2, ln1s, ln1b, ln2s, ln2b,
      (const int*)nullptr, 0, (float*)d_out + (size_t)2048*256);
  hipLaunchKernelGGL(writeout_k, dim3(2048), dim3(256), 0, stream, reprs, (float*)d_out);
}

// Round 6
// 3717.902 us; speedup vs baseline: 2.2473x; 1.3432x over previous
//
#include <hip/hip_runtime.h>
#include <stdint.h>
#include <math.h>

typedef __attribute__((ext_vector_type(8))) short bf16x8;
typedef __attribute__((ext_vector_type(4))) short s16x4;
typedef __attribute__((ext_vector_type(4))) float f32x4;
typedef unsigned short u16;

// raw barrier: LDS drain only; global (vmcnt) prefetches stay in flight
#define SBAR() asm volatile("s_waitcnt lgkmcnt(0)\ns_barrier" ::: "memory")

__device__ __forceinline__ short f2bf(float f){
  union { float f; uint32_t u; } v; v.f = f;
  uint32_t r = v.u + 0x7FFFu + ((v.u >> 16) & 1u);
  return (short)(r >> 16);
}
__device__ __forceinline__ float bf2f(u16 b){
  union { uint32_t u; float f; } v; v.u = ((uint32_t)b) << 16; return v.f;
}
// bool inputs may arrive as uint8 (numpy bool) or int32; runtime-detected flag selects.
__device__ __forceinline__ bool getb(const void* p, int i, int flag){
  if (flag) return ((const unsigned char*)p)[i] != 0;
  return ((const int*)p)[i] != 0;
}
// XOR-swizzled offset into the bf16 X buffer [64 rows][256 cols]
__device__ __forceinline__ int xoff(int row, int col){
  int g = (col >> 3) ^ (row & 7);
  return row * 256 + (g << 3) + (col & 7);
}

__global__ void detect_bool_k(const void* pad, int* flag){
  const unsigned char* b = (const unsigned char*)pad;
  int f = 0;
  for (int i = 1; i < 64; ++i) if (i & 3) f |= (b[i] != 0) ? 1 : 0;
  *flag = f;
}

// Pack f32 W [mats][K][N] into MFMA-fragment-linear bf16:
// dst[(((m*(N/16)+nt)*(K/32)+kt)*64 + lane)*8 + j] = W[m][32kt+8lg+j][16nt+li]
// -> every B-fragment load is a contiguous 1KB coalesced segment.
__global__ void pack_k(const float* __restrict__ src, u16* __restrict__ dst, int K, int N){
  long idx = (long)blockIdx.x * blockDim.x + threadIdx.x;
  int j = (int)(idx & 7);
  int lane = (int)((idx >> 3) & 63);
  long t = idx >> 9;
  int KT = K >> 5;
  int kt = (int)(t % KT);
  long t2 = t / KT;
  int NT = N >> 4;
  int nt = (int)(t2 % NT);
  int m = (int)(t2 / NT);
  int li = lane & 15, lg = lane >> 4;
  int k = 32*kt + 8*lg + j, n = 16*nt + li;
  dst[idx] = (u16)f2bf(src[((long)m * K + k) * N + n]);
}

__global__ void emb2bf_k(const float* __restrict__ src, u16* __restrict__ dst){
  long i = (long)blockIdx.x * blockDim.x + threadIdx.x;
  dst[i] = (u16)f2bf(src[i]);
}

__global__ void pos_init_k(const int* __restrict__ pos, float* __restrict__ reprs){
  int n = blockIdx.x, d = threadIdx.x;
  double p = (double)pos[n];
  int i = (d < 128) ? d : d - 128;
  double ang = p / pow(500.0, (2.0 * (double)i) / 256.0);
  reprs[n * 256 + d] = (d < 128) ? (float)sin(ang) : (float)cos(ang);
}

__global__ void zero_counts_k(int* c){ if (threadIdx.x < 4) c[threadIdx.x] = 0; }

// build per-rank live-term lists (order irrelevant; work set deterministic)
__global__ void compact_k(const int* __restrict__ sortv, int* __restrict__ lists,
                          int* __restrict__ counts){
  int t = blockIdx.x * 256 + threadIdx.x;
  int r = sortv[t];
  int pos = atomicAdd(&counts[r], 1);
  lists[r * 2048 + pos] = t;
}

__global__ void update_k(const int* __restrict__ sortv, const float* __restrict__ encCLS,
                         float* __restrict__ reprs, int rank){
  int t = blockIdx.x;
  if (sortv[t] != rank) return;
  reprs[t * 256 + threadIdx.x] += encCLS[t * 256 + threadIdx.x];
}

__global__ void writeout_k(const float* __restrict__ reprs, float* __restrict__ out){
  int i = blockIdx.x * 256 + threadIdx.x;
  out[i] = reprs[i];
}

// One block = one term, 4 waves, all 4 layers fused.
// Weights in fragment-linear layout (coalesced 1KB loads); live terms compacted.
__global__ __launch_bounds__(256, 2)
void encode_k(const int* __restrict__ tokens, const void* __restrict__ pad,
              const void* __restrict__ refm, const int* __restrict__ boolflag,
              const float* __restrict__ storage, const u16* __restrict__ embB,
              const u16* __restrict__ WqF, const u16* __restrict__ WkF,
              const u16* __restrict__ WvF, const u16* __restrict__ WoF,
              const u16* __restrict__ W1F, const float* __restrict__ b1,
              const u16* __restrict__ W2F, const float* __restrict__ b2,
              const float* __restrict__ ln1s, const float* __restrict__ ln1b,
              const float* __restrict__ ln2s, const float* __restrict__ ln2b,
              const int* __restrict__ list, const int* __restrict__ cnt,
              float* __restrict__ outCLS)
{
  int term;
  if (list){
    if ((int)blockIdx.x >= *cnt) return;
    term = list[blockIdx.x];
  } else {
    term = blockIdx.x;
  }
  const int flag = *boolflag;

  __shared__ u16 sXb[64 * 256];        // 32 KB bf16 X (swizzled)
  __shared__ u16 sPoolA[64 * 136];     // sQK | FFN hidden buf 0
  __shared__ u16 sPoolB[64 * 72 * 3];  // sVT|sO|sP | FFN hidden buf 1
  __shared__ float sStat[64][8];
  __shared__ float sMask[64];
  __shared__ int sTok[192];
  __shared__ int sRef[64];

  u16 (*sQK)[136] = (u16(*)[136])sPoolA;
  u16 (*sVT)[72]  = (u16(*)[72])sPoolB;
  u16 (*sO)[72]   = (u16(*)[72])(sPoolB + 64*72);
  u16 (*sP)[72]   = (u16(*)[72])(sPoolB + 2*64*72);
  u16 (*sH0)[136] = (u16(*)[136])sPoolA;
  u16 (*sH1)[136] = (u16(*)[136])sPoolB;

  const int tid = threadIdx.x;
  const int w = tid >> 6, lane = tid & 63, lg = lane >> 4, li = lane & 15;
  const f32x4 zero4 = {0.f, 0.f, 0.f, 0.f};

  // stage token ids + masks in LDS
  if (tid < 192) sTok[tid] = tokens[term * 192 + tid];
  if (tid < 64){
    sMask[tid] = getb(pad, term * 64 + tid, flag) ? 0.f : -1e9f;
    sRef[tid] = getb(refm, term * 64 + tid, flag) ? 1 : 0;
  }
  SBAR();

  // build X (bf16 into sXb): refmask ? storage[refids] : sum of 3 embeddings
  #pragma unroll 4
  for (int s = 0; s < 64; ++s){
    float v;
    if (sRef[s]){
      v = storage[sTok[3*s + 1] * 256 + tid];
    } else {
      v = bf2f(embB[sTok[3*s + 0] * 256 + tid])
        + bf2f(embB[(2048 + sTok[3*s + 1]) * 256 + tid])
        + bf2f(embB[(4096 + sTok[3*s + 2]) * 256 + tid]);
    }
    sXb[xoff(s, tid)] = (u16)f2bf(v);
  }
  SBAR();

  // X residual in registers at this thread's C-fragment positions
  float xres[4][4][4];
  #pragma unroll
  for (int rt = 0; rt < 4; ++rt)
    #pragma unroll
    for (int ctl = 0; ctl < 4; ++ctl)
      #pragma unroll
      for (int r = 0; r < 4; ++r)
        xres[rt][ctl][r] = bf2f(sXb[xoff(16*rt + 4*lg + r, 64*w + 16*ctl + li)]);

  // A-fragment from swizzled sXb
  auto ldA = [&](int rt, int kk) -> bf16x8 {
    return *(const bf16x8*)&sXb[(16*rt + li) * 256 + (((4*kk + lg) ^ (li & 7)) << 3)];
  };

  for (int l = 0; l < 4; ++l){
    // ================= attention (incremental Wo accumulate) =================
    f32x4 ga[4][4];
    #pragma unroll
    for (int rt = 0; rt < 4; ++rt)
      #pragma unroll
      for (int c = 0; c < 4; ++c) ga[rt][c] = zero4;

    for (int hp = 0; hp < 4; ++hp){
      // ---- QKV GEMM; fragment-linear B loads (contiguous 1KB per fragment)
      f32x4 acc[4][3];
      #pragma unroll
      for (int rt = 0; rt < 4; ++rt)
        #pragma unroll
        for (int c = 0; c < 3; ++c) acc[rt][c] = zero4;

      const u16* bF[3];
      #pragma unroll
      for (int ctl = 0; ctl < 3; ++ctl){
        int c = 48 * w + 16 * ctl;
        int mm = c >> 6;                       // 0:Q 1:K 2:V
        int nt = hp * 4 + ((c & 63) >> 4);     // global 16-col tile index
        const u16* Wt = (mm == 0) ? WqF : ((mm == 1) ? WkF : WvF);
        bF[ctl] = Wt + (((size_t)(l * 16 + nt) * 8) * 64 + lane) * 8;
      }
      bf16x8 bq[8][3];
      #pragma unroll
      for (int kt = 0; kt < 8; ++kt)
        #pragma unroll
        for (int ctl = 0; ctl < 3; ++ctl)
          bq[kt][ctl] = *(const bf16x8*)(bF[ctl] + (size_t)kt * 512);
      #pragma unroll
      for (int kt = 0; kt < 8; ++kt){
        bf16x8 a[4];
        #pragma unroll
        for (int rt = 0; rt < 4; ++rt) a[rt] = ldA(rt, kt);
        #pragma unroll
        for (int ctl = 0; ctl < 3; ++ctl)
          #pragma unroll
          for (int rt = 0; rt < 4; ++rt)
            acc[rt][ctl] = __builtin_amdgcn_mfma_f32_16x16x32_bf16(a[rt], bq[kt][ctl], acc[rt][ctl], 0, 0, 0);
      }
      // ---- scatter Q|K to sQK, V^T to sVT
      #pragma unroll
      for (int rt = 0; rt < 4; ++rt)
        #pragma unroll
        for (int ctl = 0; ctl < 3; ++ctl){
          int c = 48*w + 16*ctl;
          if (c < 128){
            #pragma unroll
            for (int r = 0; r < 4; ++r)
              sQK[16*rt + 4*lg + r][c + li] = (u16)f2bf(acc[rt][ctl][r]);
          } else {
            s16x4 pk;
            #pragma unroll
            for (int r = 0; r < 4; ++r) pk[r] = f2bf(acc[rt][ctl][r]);
            *(s16x4*)&sVT[c + li - 128][16*rt + 4*lg] = pk;
          }
        }
      // prefetch Wo B-fragments BEFORE the barrier (consumed after hh loop)
      bf16x8 woB[2][4];
      #pragma unroll
      for (int kt2 = 0; kt2 < 2; ++kt2)
        #pragma unroll
        for (int ctl = 0; ctl < 4; ++ctl)
          woB[kt2][ctl] = *(const bf16x8*)(WoF +
              (((size_t)(l*16 + 4*w + ctl) * 8 + 2*hp + kt2) * 64 + lane) * 8);
      SBAR();   // post-scatter: sQK/sVT visible

      #pragma unroll
      for (int hh = 0; hh < 2; ++hh){
        bf16x8 aq = *(const bf16x8*)&sQK[16*w + li][32*hh + 8*lg];
        f32x4 sc[4];
        #pragma unroll
        for (int ct = 0; ct < 4; ++ct){
          bf16x8 bk = *(const bf16x8*)&sQK[16*ct + li][64 + 32*hh + 8*lg];
          sc[ct] = __builtin_amdgcn_mfma_f32_16x16x32_bf16(aq, bk, zero4, 0, 0, 0);
        }
        float sv[4][4];
        #pragma unroll
        for (int ct = 0; ct < 4; ++ct){
          float mk = sMask[16*ct + li];
          #pragma unroll
          for (int r = 0; r < 4; ++r) sv[ct][r] = sc[ct][r] * 0.17677669529663687f + mk;
        }
        #pragma unroll
        for (int r = 0; r < 4; ++r){
          float m = fmaxf(fmaxf(sv[0][r], sv[1][r]), fmaxf(sv[2][r], sv[3][r]));
          #pragma unroll
          for (int o = 1; o < 16; o <<= 1) m = fmaxf(m, __shfl_xor(m, o, 64));
          float s0 = 0.f;
          #pragma unroll
          for (int ct = 0; ct < 4; ++ct){ float e = __expf(sv[ct][r] - m); sv[ct][r] = e; s0 += e; }
          #pragma unroll
          for (int o = 1; o < 16; o <<= 1) s0 += __shfl_xor(s0, o, 64);
          float inv = 1.f / s0;
          #pragma unroll
          for (int ct = 0; ct < 4; ++ct) sv[ct][r] *= inv;
        }
        // P wave-private (16-row stripe): no barriers around sP
        #pragma unroll
        for (int ct = 0; ct < 4; ++ct)
          #pragma unroll
          for (int r = 0; r < 4; ++r)
            sP[16*w + 4*lg + r][16*ct + li] = (u16)f2bf(sv[ct][r]);
        f32x4 oa[2] = {zero4, zero4};
        #pragma unroll
        for (int kt = 0; kt < 2; ++kt){
          bf16x8 ap = *(const bf16x8*)&sP[16*w + li][32*kt + 8*lg];
          #pragma unroll
          for (int ct = 0; ct < 2; ++ct){
            bf16x8 bv = *(const bf16x8*)&sVT[32*hh + 16*ct + li][32*kt + 8*lg];
            oa[ct] = __builtin_amdgcn_mfma_f32_16x16x32_bf16(ap, bv, oa[ct], 0, 0, 0);
          }
        }
        #pragma unroll
        for (int ct = 0; ct < 2; ++ct)
          #pragma unroll
          for (int r = 0; r < 4; ++r)
            sO[16*w + 4*lg + r][32*hh + 16*ct + li] = (u16)f2bf(oa[ct][r]);
      }
      SBAR();   // sO complete (also guards next hp's scatter)
      // partial Wo: ga += O[:, 64hp:64hp+64) @ Wo[64hp:64hp+64, :]
      #pragma unroll
      for (int kt2 = 0; kt2 < 2; ++kt2){
        bf16x8 a[4];
        #pragma unroll
        for (int rt = 0; rt < 4; ++rt)
          a[rt] = *(const bf16x8*)&sO[16*rt + li][32*kt2 + 8*lg];
        #pragma unroll
        for (int ctl = 0; ctl < 4; ++ctl)
          #pragma unroll
          for (int rt = 0; rt < 4; ++rt)
            ga[rt][ctl] = __builtin_amdgcn_mfma_f32_16x16x32_bf16(a[rt], woB[kt2][ctl], ga[rt][ctl], 0, 0, 0);
      }
    } // hp

    // ================= residual + LN1 (regs -> sXb) =================
    {
      float g4[4], bb4[4];
      #pragma unroll
      for (int ctl = 0; ctl < 4; ++ctl){
        int col = 64*w + 16*ctl + li;
        g4[ctl] = ln1s[l*256 + col]; bb4[ctl] = ln1b[l*256 + col];
      }
      float s1v[4][4], s2v[4][4];
      #pragma unroll
      for (int rt = 0; rt < 4; ++rt)
        #pragma unroll
        for (int r = 0; r < 4; ++r){
          float t1 = 0.f, t2 = 0.f;
          #pragma unroll
          for (int ctl = 0; ctl < 4; ++ctl){
            float y = ga[rt][ctl][r] + xres[rt][ctl][r];
            ga[rt][ctl][r] = y; t1 += y; t2 += y * y;
          }
          #pragma unroll
          for (int o = 1; o < 16; o <<= 1){ t1 += __shfl_xor(t1, o, 64); t2 += __shfl_xor(t2, o, 64); }
          s1v[rt][r] = t1; s2v[rt][r] = t2;
        }
      if (li == 0){
        #pragma unroll
        for (int rt = 0; rt < 4; ++rt)
          #pragma unroll
          for (int r = 0; r < 4; ++r){
            sStat[16*rt + 4*lg + r][w] = s1v[rt][r];
            sStat[16*rt + 4*lg + r][4 + w] = s2v[rt][r];
          }
      }
      SBAR();
      #pragma unroll
      for (int rt = 0; rt < 4; ++rt)
        #pragma unroll
        for (int r = 0; r < 4; ++r){
          int row = 16*rt + 4*lg + r;
          float su = sStat[row][0] + sStat[row][1] + sStat[row][2] + sStat[row][3];
          float sq = sStat[row][4] + sStat[row][5] + sStat[row][6] + sStat[row][7];
          float mean = su * (1.f / 256.f);
          float var = sq * (1.f / 256.f) - mean * mean;
          float rs = rsqrtf(var + 1e-5f);
          #pragma unroll
          for (int ctl = 0; ctl < 4; ++ctl){
            int col = 64*w + 16*ctl + li;
            float nv = (ga[rt][ctl][r] - mean) * rs * g4[ctl] + bb4[ctl];
            xres[rt][ctl][r] = nv;
            sXb[xoff(row, col)] = (u16)f2bf(nv);
          }
        }
      SBAR();
    }

    // ================= FFN: double-buffered hidden, pipelined W loads =================
    {
      float b1v[8][2];
      #pragma unroll
      for (int ch = 0; ch < 8; ++ch)
        #pragma unroll
        for (int ctl = 0; ctl < 2; ++ctl)
          b1v[ch][ctl] = b1[l*1024 + 128*ch + 32*w + 16*ctl + li];

      bf16x8 w1f[2][8];
      auto loadW1 = [&](int ch){
        #pragma unroll
        for (int ctl = 0; ctl < 2; ++ctl){
          const u16* p0 = W1F + (((size_t)(l*64 + 8*ch + 2*w + ctl) * 8) * 64 + lane) * 8;
          #pragma unroll
          for (int kt = 0; kt < 8; ++kt)
            w1f[ctl][kt] = *(const bf16x8*)(p0 + (size_t)kt * 512);
        }
      };
      auto mfma1 = [&](f32x4 (*h)[2]){
        #pragma unroll
        for (int rt = 0; rt < 4; ++rt){ h[rt][0] = zero4; h[rt][1] = zero4; }
        #pragma unroll
        for (int kt = 0; kt < 8; ++kt){
          bf16x8 a[4];
          #pragma unroll
          for (int rt = 0; rt < 4; ++rt) a[rt] = ldA(rt, kt);
          #pragma unroll
          for (int ctl = 0; ctl < 2; ++ctl)
            #pragma unroll
            for (int rt = 0; rt < 4; ++rt)
              h[rt][ctl] = __builtin_amdgcn_mfma_f32_16x16x32_bf16(a[rt], w1f[ctl][kt], h[rt][ctl], 0, 0, 0);
        }
      };

      f32x4 fa[4][4];
      #pragma unroll
      for (int rt = 0; rt < 4; ++rt)
        #pragma unroll
        for (int c = 0; c < 4; ++c) fa[rt][c] = zero4;

      f32x4 haA[4][2], haB[4][2];
      loadW1(0);
      mfma1(haA);

      #pragma unroll
      for (int ch = 0; ch < 8; ++ch){
        f32x4 (*cur)[2] = (ch & 1) ? haB : haA;
        f32x4 (*nxt)[2] = (ch & 1) ? haA : haB;
        u16 (*sHc)[136] = (ch & 1) ? sH1 : sH0;
        #pragma unroll
        for (int rt = 0; rt < 4; ++rt)
          #pragma unroll
          for (int ctl = 0; ctl < 2; ++ctl)
            #pragma unroll
            for (int r = 0; r < 4; ++r){
              float v = cur[rt][ctl][r] + b1v[ch][ctl];
              sHc[16*rt + 4*lg + r][32*w + 16*ctl + li] = (u16)f2bf(fmaxf(v, 0.f));
            }
        // pre-barrier issue of W2(ch) first half; survives the raw barrier
        bf16x8 w2a[2][4];
        #pragma unroll
        for (int kt = 0; kt < 2; ++kt)
          #pragma unroll
          for (int ctl = 0; ctl < 4; ++ctl)
            w2a[kt][ctl] = *(const bf16x8*)(W2F +
                (((size_t)(l*16 + 4*w + ctl) * 32 + 4*ch + kt) * 64 + lane) * 8);
        SBAR();    // hidden chunk visible
        if (ch < 7) loadW1(ch + 1);   // next GEMM1 weights; hidden under GEMM2
        // GEMM2(ch) first half (w2a resident)
        #pragma unroll
        for (int kt = 0; kt < 2; ++kt){
          bf16x8 a[4];
          #pragma unroll
          for (int rt = 0; rt < 4; ++rt)
            a[rt] = *(const bf16x8*)&sHc[16*rt + li][32*kt + 8*lg];
          #pragma unroll
          for (int ctl = 0; ctl < 4; ++ctl)
            #pragma unroll
            for (int rt = 0; rt < 4; ++rt)
              fa[rt][ctl] = __builtin_amdgcn_mfma_f32_16x16x32_bf16(a[rt], w2a[kt][ctl], fa[rt][ctl], 0, 0, 0);
        }
        // GEMM2(ch) second half
        #pragma unroll
        for (int kt = 2; kt < 4; ++kt){
          bf16x8 br[4];
          #pragma unroll
          for (int ctl = 0; ctl < 4; ++ctl)
            br[ctl] = *(const bf16x8*)(W2F +
                (((size_t)(l*16 + 4*w + ctl) * 32 + 4*ch + kt) * 64 + lane) * 8);
          bf16x8 a[4];
          #pragma unroll
          for (int rt = 0; rt < 4; ++rt)
            a[rt] = *(const bf16x8*)&sHc[16*rt + li][32*kt + 8*lg];
          #pragma unroll
          for (int ctl = 0; ctl < 4; ++ctl)
            #pragma unroll
            for (int rt = 0; rt < 4; ++rt)
              fa[rt][ctl] = __builtin_amdgcn_mfma_f32_16x16x32_bf16(a[rt], br[ctl], fa[rt][ctl], 0, 0, 0);
        }
        if (ch < 7) mfma1(nxt);   // W1 arrived during GEMM2
      }

      // ---- residual + bias + LN2
      float g4[4], bb4[4], b2v[4];
      #pragma unroll
      for (int ctl = 0; ctl < 4; ++ctl){
        int col = 64*w + 16*ctl + li;
        g4[ctl] = ln2s[l*256 + col]; bb4[ctl] = ln2b[l*256 + col]; b2v[ctl] = b2[l*256 + col];
      }
      float s1v[4][4], s2v[4][4];
      #pragma unroll
      for (int rt = 0; rt < 4; ++rt)
        #pragma unroll
        for (int r = 0; r < 4; ++r){
          float t1 = 0.f, t2 = 0.f;
          #pragma unroll
          for (int ctl = 0; ctl < 4; ++ctl){
            float y = fa[rt][ctl][r] + xres[rt][ctl][r] + b2v[ctl];
            fa[rt][ctl][r] = y; t1 += y; t2 += y * y;
          }
          #pragma unroll
          for (int o = 1; o < 16; o <<= 1){ t1 += __shfl_xor(t1, o, 64); t2 += __shfl_xor(t2, o, 64); }
          s1v[rt][r] = t1; s2v[rt][r] = t2;
        }
      if (li == 0){
        #pragma unroll
        for (int rt = 0; rt < 4; ++rt)
          #pragma unroll
          for (int r = 0; r < 4; ++r){
            sStat[16*rt + 4*lg + r][w] = s1v[rt][r];
            sStat[16*rt + 4*lg + r][4 + w] = s2v[rt][r];
          }
      }
      SBAR();
      #pragma unroll
      for (int rt = 0; rt < 4; ++rt)
        #pragma unroll
        for (int r = 0; r < 4; ++r){
          int row = 16*rt + 4*lg + r;
          float su = sStat[row][0] + sStat[row][1] + sStat[row][2] + sStat[row][3];
          float sq = sStat[row][4] + sStat[row][5] + sStat[row][6] + sStat[row][7];
          float mean = su * (1.f / 256.f);
          float var = sq * (1.f / 256.f) - mean * mean;
          float rs = rsqrtf(var + 1e-5f);
          #pragma unroll
          for (int ctl = 0; ctl < 4; ++ctl){
            int col = 64*w + 16*ctl + li;
            float nv = (fa[rt][ctl][r] - mean) * rs * g4[ctl] + bb4[ctl];
            xres[rt][ctl][r] = nv;
            sXb[xoff(row, col)] = (u16)f2bf(nv);
            if (l == 3 && outCLS && row == 0) outCLS[term * 256 + col] = nv;
          }
        }
      SBAR();
    }
  }
}

extern "C" void kernel_launch(void* const* d_in, const int* in_sizes, int n_in,
                              void* d_out, int out_size, void* d_ws, size_t ws_size,
                              hipStream_t stream)
{
  (void)in_sizes; (void)n_in; (void)out_size; (void)ws_size;
  const int* tokens_scope = (const int*)d_in[0];
  const int* tokens_hole  = (const int*)d_in[1];
  const void* pad_scope = d_in[2];
  const void* pad_hole  = d_in[3];
  const void* ref_scope = d_in[4];
  const void* ref_hole  = d_in[5];
  const int* scope_sort = (const int*)d_in[6];
  const int* scope_pos  = (const int*)d_in[7];
  const float* emb  = (const float*)d_in[8];
  const float* Wq   = (const float*)d_in[9];
  const float* Wk   = (const float*)d_in[10];
  const float* Wv   = (const float*)d_in[11];
  const float* Wo   = (const float*)d_in[12];
  const float* ln1s = (const float*)d_in[13];
  const float* ln1b = (const float*)d_in[14];
  const float* W1   = (const float*)d_in[15];
  const float* b1   = (const float*)d_in[16];
  const float* W2   = (const float*)d_in[17];
  const float* b2   = (const float*)d_in[18];
  const float* ln2s = (const float*)d_in[19];
  const float* ln2b = (const float*)d_in[20];

  char* p = (char*)d_ws;
  float* reprs  = (float*)p; p += (size_t)2048*256*4;
  float* encCLS = (float*)p; p += (size_t)2048*256*4;
  u16* WqF = (u16*)p; p += (size_t)4*256*256*2;
  u16* WkF = (u16*)p; p += (size_t)4*256*256*2;
  u16* WvF = (u16*)p; p += (size_t)4*256*256*2;
  u16* WoF = (u16*)p; p += (size_t)4*256*256*2;
  u16* W1F = (u16*)p; p += (size_t)4*256*1024*2;
  u16* W2F = (u16*)p; p += (size_t)4*256*1024*2;
  u16* embB = (u16*)p; p += (size_t)3*2048*256*2;
  int* lists = (int*)p; p += (size_t)4*2048*4;
  int* counts = (int*)p; p += 64;
  int* flag = (int*)p; p += 16;

  hipLaunchKernelGGL(detect_bool_k, dim3(1), dim3(1), 0, stream, pad_scope, flag);
  hipLaunchKernelGGL(emb2bf_k, dim3(6144), dim3(256), 0, stream, emb, embB);
  hipLaunchKernelGGL(pack_k, dim3(1024), dim3(256), 0, stream, Wq, WqF, 256, 256);
  hipLaunchKernelGGL(pack_k, dim3(1024), dim3(256), 0, stream, Wk, WkF, 256, 256);
  hipLaunchKernelGGL(pack_k, dim3(1024), dim3(256), 0, stream, Wv, WvF, 256, 256);
  hipLaunchKernelGGL(pack_k, dim3(1024), dim3(256), 0, stream, Wo, WoF, 256, 256);
  hipLaunchKernelGGL(pack_k, dim3(4096), dim3(256), 0, stream, W1, W1F, 256, 1024);
  hipLaunchKernelGGL(pack_k, dim3(4096), dim3(256), 0, stream, W2, W2F, 1024, 256);
  hipLaunchKernelGGL(pos_init_k, dim3(2048), dim3(256), 0, stream, scope_pos, reprs);
  hipLaunchKernelGGL(zero_counts_k, dim3(1), dim3(64), 0, stream, counts);
  hipLaunchKernelGGL(compact_k, dim3(8), dim3(256), 0, stream, scope_sort, lists, counts);

  for (int r = 0; r < 4; ++r){
    hipLaunchKernelGGL(encode_k, dim3(2048), dim3(256), 0, stream,
      tokens_scope, pad_scope, ref_scope, flag, reprs, embB,
      WqF, WkF, WvF, WoF, W1F, b1, W2F, b2, ln1s, ln1b, ln2s, ln2b,
      lists + (size_t)r*2048, counts + r, encCLS);
    hipLaunchKernelGGL(update_k, dim3(2048), dim3(256), 0, stream, scope_sort, encCLS, reprs, r);
  }
  hipLaunchKernelGGL(encode_k, dim3(512), dim3(256), 0, stream,
      tokens_hole, pad_hole, ref_hole, flag, reprs, embB,
      WqF, WkF, WvF, WoF, W1F, b1, W2F, b2, ln1s, ln1b, ln2s, ln2b,
      (const int*)nullptr, (const int*)nullptr, (float*)d_out + (size_t)2048*256);
  hipLaunchKernelGGL(writeout_k, dim3(2048), dim3(256), 0, stream, reprs, (float*)d_out);
}

// Round 7
// 2796.306 us; speedup vs baseline: 2.9879x; 1.3296x over previous
//
#include <hip/hip_runtime.h>
#include <stdint.h>
#include <math.h>

typedef __attribute__((ext_vector_type(8))) short bf16x8;
typedef __attribute__((ext_vector_type(4))) short s16x4;
typedef __attribute__((ext_vector_type(4))) float f32x4;
typedef unsigned short u16;

// raw barrier: LDS drain only; global (vmcnt) prefetches stay in flight
#define SBAR() asm volatile("s_waitcnt lgkmcnt(0)\ns_barrier" ::: "memory")

__device__ __forceinline__ short f2bf(float f){
  union { float f; uint32_t u; } v; v.f = f;
  uint32_t r = v.u + 0x7FFFu + ((v.u >> 16) & 1u);
  return (short)(r >> 16);
}
__device__ __forceinline__ float bf2f(u16 b){
  union { uint32_t u; float f; } v; v.u = ((uint32_t)b) << 16; return v.f;
}
__device__ __forceinline__ bool getb(const void* p, int i, int flag){
  if (flag) return ((const unsigned char*)p)[i] != 0;
  return ((const int*)p)[i] != 0;
}
// XOR-swizzled offset into the bf16 X buffer [64 rows][256 cols]
__device__ __forceinline__ int xoff(int row, int col){
  int g = (col >> 3) ^ (row & 7);
  return row * 256 + (g << 3) + (col & 7);
}

__global__ void detect_bool_k(const void* pad, int* flag){
  const unsigned char* b = (const unsigned char*)pad;
  int f = 0;
  for (int i = 1; i < 64; ++i) if (i & 3) f |= (b[i] != 0) ? 1 : 0;
  *flag = f;
}

// Pack f32 W [mats][K][N] into MFMA-fragment-linear bf16:
// dst[(((m*(N/16)+nt)*(K/32)+kt)*64 + lane)*8 + j] = W[m][32kt+8lg+j][16nt+li]
__global__ void pack_k(const float* __restrict__ src, u16* __restrict__ dst, int K, int N){
  long idx = (long)blockIdx.x * blockDim.x + threadIdx.x;
  int j = (int)(idx & 7);
  int lane = (int)((idx >> 3) & 63);
  long t = idx >> 9;
  int KT = K >> 5;
  int kt = (int)(t % KT);
  long t2 = t / KT;
  int NT = N >> 4;
  int nt = (int)(t2 % NT);
  int m = (int)(t2 / NT);
  int li = lane & 15, lg = lane >> 4;
  int k = 32*kt + 8*lg + j, n = 16*nt + li;
  dst[idx] = (u16)f2bf(src[((long)m * K + k) * N + n]);
}

__global__ void emb2bf_k(const float* __restrict__ src, u16* __restrict__ dst){
  long i = (long)blockIdx.x * blockDim.x + threadIdx.x;
  dst[i] = (u16)f2bf(src[i]);
}

__global__ void pos_init_k(const int* __restrict__ pos, float* __restrict__ reprs){
  int n = blockIdx.x, d = threadIdx.x;
  double p = (double)pos[n];
  int i = (d < 128) ? d : d - 128;
  double ang = p / pow(500.0, (2.0 * (double)i) / 256.0);
  reprs[n * 256 + d] = (d < 128) ? (float)sin(ang) : (float)cos(ang);
}

__global__ void zero_counts_k(int* c){ if (threadIdx.x < 4) c[threadIdx.x] = 0; }

__global__ void compact_k(const int* __restrict__ sortv, int* __restrict__ lists,
                          int* __restrict__ counts){
  int t = blockIdx.x * 256 + threadIdx.x;
  int r = sortv[t];
  int pos = atomicAdd(&counts[r], 1);
  lists[r * 2048 + pos] = t;
}

__global__ void update_k(const int* __restrict__ sortv, const float* __restrict__ encCLS,
                         float* __restrict__ reprs, int rank){
  int t = blockIdx.x;
  if (sortv[t] != rank) return;
  reprs[t * 256 + threadIdx.x] += encCLS[t * 256 + threadIdx.x];
}

__global__ void writeout_k(const float* __restrict__ reprs, float* __restrict__ out){
  int i = blockIdx.x * 256 + threadIdx.x;
  out[i] = reprs[i];
}

// One block = one term, 8 waves (512 threads), all 4 layers fused.
// Wave (wr,wc): wr=row-half (32 rows), wc=col-quarter (64 cols). 2 waves/SIMD.
// Attention: wave handles q-stripe wc of head wr (heads concurrent across row-waves).
__global__ __launch_bounds__(512, 2)
void encode_k(const int* __restrict__ tokens, const void* __restrict__ pad,
              const void* __restrict__ refm, const int* __restrict__ boolflag,
              const float* __restrict__ storage, const u16* __restrict__ embB,
              const u16* __restrict__ WqF, const u16* __restrict__ WkF,
              const u16* __restrict__ WvF, const u16* __restrict__ WoF,
              const u16* __restrict__ W1F, const float* __restrict__ b1,
              const u16* __restrict__ W2F, const float* __restrict__ b2,
              const float* __restrict__ ln1s, const float* __restrict__ ln1b,
              const float* __restrict__ ln2s, const float* __restrict__ ln2b,
              const int* __restrict__ list, const int* __restrict__ cnt,
              float* __restrict__ outCLS)
{
  int term;
  if (list){
    if ((int)blockIdx.x >= *cnt) return;
    term = list[blockIdx.x];
  } else {
    term = blockIdx.x;
  }
  const int flag = *boolflag;

  __shared__ u16 sXb[64 * 256];        // 32 KB bf16 X (swizzled)
  __shared__ u16 sPoolA[64 * 136];     // sQK | FFN hidden buf 0 (17.4 KB)
  __shared__ u16 sPoolB[64 * 72 * 2];  // sVT | sO (18 KB)
  __shared__ u16 sPbuf[2 * 64 * 72];   // per-head P | FFN hidden buf 1 (18 KB)
  __shared__ float sStat[64][8];
  __shared__ float sMask[64];
  __shared__ int sTok[192];
  __shared__ int sRef[64];

  u16 (*sQK)[136] = (u16(*)[136])sPoolA;
  u16 (*sVT)[72]  = (u16(*)[72])sPoolB;
  u16 (*sO)[72]   = (u16(*)[72])(sPoolB + 64*72);
  u16 (*sH0)[136] = (u16(*)[136])sPoolA;
  u16 (*sH1)[136] = (u16(*)[136])sPbuf;

  const int tid = threadIdx.x;
  const int w = tid >> 6, lane = tid & 63, lg = lane >> 4, li = lane & 15;
  const int wr = w >> 2, wc = w & 3;
  const int rbase = 32 * wr;           // this wave's row base
  const f32x4 zero4 = {0.f, 0.f, 0.f, 0.f};

  if (tid < 192) sTok[tid] = tokens[term * 192 + tid];
  if (tid < 64){
    sMask[tid] = getb(pad, term * 64 + tid, flag) ? 0.f : -1e9f;
    sRef[tid] = getb(refm, term * 64 + tid, flag) ? 1 : 0;
  }
  SBAR();

  // build X: 512 threads -> two row-halves in parallel
  {
    int col = tid & 255, rh = tid >> 8;
    #pragma unroll 4
    for (int s = 32*rh; s < 32*rh + 32; ++s){
      float v;
      if (sRef[s]){
        v = storage[sTok[3*s + 1] * 256 + col];
      } else {
        v = bf2f(embB[sTok[3*s + 0] * 256 + col])
          + bf2f(embB[(2048 + sTok[3*s + 1]) * 256 + col])
          + bf2f(embB[(4096 + sTok[3*s + 2]) * 256 + col]);
      }
      sXb[xoff(s, col)] = (u16)f2bf(v);
    }
  }
  SBAR();

  // X residual in registers at this thread's C-fragment positions
  float xres[2][4][4];
  #pragma unroll
  for (int rt = 0; rt < 2; ++rt)
    #pragma unroll
    for (int ctl = 0; ctl < 4; ++ctl)
      #pragma unroll
      for (int r = 0; r < 4; ++r)
        xres[rt][ctl][r] = bf2f(sXb[xoff(rbase + 16*rt + 4*lg + r, 64*wc + 16*ctl + li)]);

  auto ldA = [&](int rt, int kk) -> bf16x8 {
    return *(const bf16x8*)&sXb[(rbase + 16*rt + li) * 256 + (((4*kk + lg) ^ (li & 7)) << 3)];
  };

  for (int l = 0; l < 4; ++l){
    // ================= attention (incremental Wo accumulate) =================
    f32x4 ga[2][4];
    #pragma unroll
    for (int rt = 0; rt < 2; ++rt)
      #pragma unroll
      for (int c = 0; c < 4; ++c) ga[rt][c] = zero4;

    for (int hp = 0; hp < 4; ++hp){
      // ---- QKV GEMM (local cols 0..191 = Q|K|V; wave cols 48*wc..48*wc+47)
      f32x4 acc[2][3];
      #pragma unroll
      for (int rt = 0; rt < 2; ++rt)
        #pragma unroll
        for (int c = 0; c < 3; ++c) acc[rt][c] = zero4;

      const u16* bF[3];
      #pragma unroll
      for (int ctl = 0; ctl < 3; ++ctl){
        int c = 48 * wc + 16 * ctl;
        int mm = c >> 6;                       // 0:Q 1:K 2:V
        int nt = hp * 4 + ((c & 63) >> 4);
        const u16* Wt = (mm == 0) ? WqF : ((mm == 1) ? WkF : WvF);
        bF[ctl] = Wt + (((size_t)(l * 16 + nt) * 8) * 64 + lane) * 8;
      }
      bf16x8 bq[8][3];
      #pragma unroll
      for (int kt = 0; kt < 8; ++kt)
        #pragma unroll
        for (int ctl = 0; ctl < 3; ++ctl)
          bq[kt][ctl] = *(const bf16x8*)(bF[ctl] + (size_t)kt * 512);
      #pragma unroll
      for (int kt = 0; kt < 8; ++kt){
        bf16x8 a[2];
        #pragma unroll
        for (int rt = 0; rt < 2; ++rt) a[rt] = ldA(rt, kt);
        #pragma unroll
        for (int ctl = 0; ctl < 3; ++ctl)
          #pragma unroll
          for (int rt = 0; rt < 2; ++rt)
            acc[rt][ctl] = __builtin_amdgcn_mfma_f32_16x16x32_bf16(a[rt], bq[kt][ctl], acc[rt][ctl], 0, 0, 0);
      }
      // ---- scatter Q|K to sQK, V^T to sVT
      #pragma unroll
      for (int rt = 0; rt < 2; ++rt)
        #pragma unroll
        for (int ctl = 0; ctl < 3; ++ctl){
          int c = 48*wc + 16*ctl;
          if (c < 128){
            #pragma unroll
            for (int r = 0; r < 4; ++r)
              sQK[rbase + 16*rt + 4*lg + r][c + li] = (u16)f2bf(acc[rt][ctl][r]);
          } else {
            s16x4 pk;
            #pragma unroll
            for (int r = 0; r < 4; ++r) pk[r] = f2bf(acc[rt][ctl][r]);
            *(s16x4*)&sVT[c + li - 128][rbase + 16*rt + 4*lg] = pk;
          }
        }
      // prefetch Wo B-fragments before the barrier (consumed after attention)
      bf16x8 woB[2][4];
      #pragma unroll
      for (int kt2 = 0; kt2 < 2; ++kt2)
        #pragma unroll
        for (int ctl = 0; ctl < 4; ++ctl)
          woB[kt2][ctl] = *(const bf16x8*)(WoF +
              (((size_t)(l*16 + 4*wc + ctl) * 8 + 2*hp + kt2) * 64 + lane) * 8);
      SBAR();   // post-scatter: sQK/sVT visible

      // ---- attention: this wave = q-stripe wc of head wr
      {
        const int hh = wr, qs = wc;
        u16 (*sP)[72] = (u16(*)[72])(sPbuf + hh * 64 * 72);
        bf16x8 aq = *(const bf16x8*)&sQK[16*qs + li][32*hh + 8*lg];
        f32x4 sc[4];
        #pragma unroll
        for (int ct = 0; ct < 4; ++ct){
          bf16x8 bk = *(const bf16x8*)&sQK[16*ct + li][64 + 32*hh + 8*lg];
          sc[ct] = __builtin_amdgcn_mfma_f32_16x16x32_bf16(aq, bk, zero4, 0, 0, 0);
        }
        float sv[4][4];
        #pragma unroll
        for (int ct = 0; ct < 4; ++ct){
          float mk = sMask[16*ct + li];
          #pragma unroll
          for (int r = 0; r < 4; ++r) sv[ct][r] = sc[ct][r] * 0.17677669529663687f + mk;
        }
        #pragma unroll
        for (int r = 0; r < 4; ++r){
          float m = fmaxf(fmaxf(sv[0][r], sv[1][r]), fmaxf(sv[2][r], sv[3][r]));
          #pragma unroll
          for (int o = 1; o < 16; o <<= 1) m = fmaxf(m, __shfl_xor(m, o, 64));
          float s0 = 0.f;
          #pragma unroll
          for (int ct = 0; ct < 4; ++ct){ float e = __expf(sv[ct][r] - m); sv[ct][r] = e; s0 += e; }
          #pragma unroll
          for (int o = 1; o < 16; o <<= 1) s0 += __shfl_xor(s0, o, 64);
          float inv = 1.f / s0;
          #pragma unroll
          for (int ct = 0; ct < 4; ++ct) sv[ct][r] *= inv;
        }
        // P wave-private (head hh, stripe qs): no barriers needed
        #pragma unroll
        for (int ct = 0; ct < 4; ++ct)
          #pragma unroll
          for (int r = 0; r < 4; ++r)
            sP[16*qs + 4*lg + r][16*ct + li] = (u16)f2bf(sv[ct][r]);
        f32x4 oa[2] = {zero4, zero4};
        #pragma unroll
        for (int kt = 0; kt < 2; ++kt){
          bf16x8 ap = *(const bf16x8*)&sP[16*qs + li][32*kt + 8*lg];
          #pragma unroll
          for (int ct = 0; ct < 2; ++ct){
            bf16x8 bv = *(const bf16x8*)&sVT[32*hh + 16*ct + li][32*kt + 8*lg];
            oa[ct] = __builtin_amdgcn_mfma_f32_16x16x32_bf16(ap, bv, oa[ct], 0, 0, 0);
          }
        }
        #pragma unroll
        for (int ct = 0; ct < 2; ++ct)
          #pragma unroll
          for (int r = 0; r < 4; ++r)
            sO[16*qs + 4*lg + r][32*hh + 16*ct + li] = (u16)f2bf(oa[ct][r]);
      }
      SBAR();   // sO complete (also guards next hp's scatter)
      // partial Wo: ga += O[:, 64hp:64hp+64) @ Wo[64hp:64hp+64, :]
      #pragma unroll
      for (int kt2 = 0; kt2 < 2; ++kt2){
        bf16x8 a[2];
        #pragma unroll
        for (int rt = 0; rt < 2; ++rt)
          a[rt] = *(const bf16x8*)&sO[rbase + 16*rt + li][32*kt2 + 8*lg];
        #pragma unroll
        for (int ctl = 0; ctl < 4; ++ctl)
          #pragma unroll
          for (int rt = 0; rt < 2; ++rt)
            ga[rt][ctl] = __builtin_amdgcn_mfma_f32_16x16x32_bf16(a[rt], woB[kt2][ctl], ga[rt][ctl], 0, 0, 0);
      }
    } // hp

    // ================= residual + LN1 (regs -> sXb) =================
    {
      float g4[4], bb4[4];
      #pragma unroll
      for (int ctl = 0; ctl < 4; ++ctl){
        int col = 64*wc + 16*ctl + li;
        g4[ctl] = ln1s[l*256 + col]; bb4[ctl] = ln1b[l*256 + col];
      }
      float s1v[2][4], s2v[2][4];
      #pragma unroll
      for (int rt = 0; rt < 2; ++rt)
        #pragma unroll
        for (int r = 0; r < 4; ++r){
          float t1 = 0.f, t2 = 0.f;
          #pragma unroll
          for (int ctl = 0; ctl < 4; ++ctl){
            float y = ga[rt][ctl][r] + xres[rt][ctl][r];
            ga[rt][ctl][r] = y; t1 += y; t2 += y * y;
          }
          #pragma unroll
          for (int o = 1; o < 16; o <<= 1){ t1 += __shfl_xor(t1, o, 64); t2 += __shfl_xor(t2, o, 64); }
          s1v[rt][r] = t1; s2v[rt][r] = t2;
        }
      if (li == 0){
        #pragma unroll
        for (int rt = 0; rt < 2; ++rt)
          #pragma unroll
          for (int r = 0; r < 4; ++r){
            sStat[rbase + 16*rt + 4*lg + r][wc] = s1v[rt][r];
            sStat[rbase + 16*rt + 4*lg + r][4 + wc] = s2v[rt][r];
          }
      }
      SBAR();
      #pragma unroll
      for (int rt = 0; rt < 2; ++rt)
        #pragma unroll
        for (int r = 0; r < 4; ++r){
          int row = rbase + 16*rt + 4*lg + r;
          float su = sStat[row][0] + sStat[row][1] + sStat[row][2] + sStat[row][3];
          float sq = sStat[row][4] + sStat[row][5] + sStat[row][6] + sStat[row][7];
          float mean = su * (1.f / 256.f);
          float var = sq * (1.f / 256.f) - mean * mean;
          float rs = rsqrtf(var + 1e-5f);
          #pragma unroll
          for (int ctl = 0; ctl < 4; ++ctl){
            int col = 64*wc + 16*ctl + li;
            float nv = (ga[rt][ctl][r] - mean) * rs * g4[ctl] + bb4[ctl];
            xres[rt][ctl][r] = nv;
            sXb[xoff(row, col)] = (u16)f2bf(nv);
          }
        }
      SBAR();
    }

    // ================= FFN: double-buffered hidden, pipelined W loads =================
    {
      float b1v[8][2];
      #pragma unroll
      for (int ch = 0; ch < 8; ++ch)
        #pragma unroll
        for (int ctl = 0; ctl < 2; ++ctl)
          b1v[ch][ctl] = b1[l*1024 + 128*ch + 32*wc + 16*ctl + li];

      bf16x8 w1f[2][8];
      auto loadW1 = [&](int ch){
        #pragma unroll
        for (int ctl = 0; ctl < 2; ++ctl){
          const u16* p0 = W1F + (((size_t)(l*64 + 8*ch + 2*wc + ctl) * 8) * 64 + lane) * 8;
          #pragma unroll
          for (int kt = 0; kt < 8; ++kt)
            w1f[ctl][kt] = *(const bf16x8*)(p0 + (size_t)kt * 512);
        }
      };
      auto mfma1 = [&](f32x4 (*h)[2]){
        #pragma unroll
        for (int rt = 0; rt < 2; ++rt){ h[rt][0] = zero4; h[rt][1] = zero4; }
        #pragma unroll
        for (int kt = 0; kt < 8; ++kt){
          bf16x8 a[2];
          #pragma unroll
          for (int rt = 0; rt < 2; ++rt) a[rt] = ldA(rt, kt);
          #pragma unroll
          for (int ctl = 0; ctl < 2; ++ctl)
            #pragma unroll
            for (int rt = 0; rt < 2; ++rt)
              h[rt][ctl] = __builtin_amdgcn_mfma_f32_16x16x32_bf16(a[rt], w1f[ctl][kt], h[rt][ctl], 0, 0, 0);
        }
      };

      f32x4 fa[2][4];
      #pragma unroll
      for (int rt = 0; rt < 2; ++rt)
        #pragma unroll
        for (int c = 0; c < 4; ++c) fa[rt][c] = zero4;

      f32x4 haA[2][2], haB[2][2];
      loadW1(0);
      mfma1(haA);

      #pragma unroll
      for (int ch = 0; ch < 8; ++ch){
        f32x4 (*cur)[2] = (ch & 1) ? haB : haA;
        f32x4 (*nxt)[2] = (ch & 1) ? haA : haB;
        u16 (*sHc)[136] = (ch & 1) ? sH1 : sH0;
        #pragma unroll
        for (int rt = 0; rt < 2; ++rt)
          #pragma unroll
          for (int ctl = 0; ctl < 2; ++ctl)
            #pragma unroll
            for (int r = 0; r < 4; ++r){
              float v = cur[rt][ctl][r] + b1v[ch][ctl];
              sHc[rbase + 16*rt + 4*lg + r][32*wc + 16*ctl + li] = (u16)f2bf(fmaxf(v, 0.f));
            }
        // pre-barrier issue of W2(ch) first half; survives the raw barrier
        bf16x8 w2a[2][4];
        #pragma unroll
        for (int kt = 0; kt < 2; ++kt)
          #pragma unroll
          for (int ctl = 0; ctl < 4; ++ctl)
            w2a[kt][ctl] = *(const bf16x8*)(W2F +
                (((size_t)(l*16 + 4*wc + ctl) * 32 + 4*ch + kt) * 64 + lane) * 8);
        SBAR();    // hidden chunk visible
        if (ch < 7) loadW1(ch + 1);
        // GEMM2(ch) first half
        #pragma unroll
        for (int kt = 0; kt < 2; ++kt){
          bf16x8 a[2];
          #pragma unroll
          for (int rt = 0; rt < 2; ++rt)
            a[rt] = *(const bf16x8*)&sHc[rbase + 16*rt + li][32*kt + 8*lg];
          #pragma unroll
          for (int ctl = 0; ctl < 4; ++ctl)
            #pragma unroll
            for (int rt = 0; rt < 2; ++rt)
              fa[rt][ctl] = __builtin_amdgcn_mfma_f32_16x16x32_bf16(a[rt], w2a[kt][ctl], fa[rt][ctl], 0, 0, 0);
        }
        // GEMM2(ch) second half
        #pragma unroll
        for (int kt = 2; kt < 4; ++kt){
          bf16x8 br[4];
          #pragma unroll
          for (int ctl = 0; ctl < 4; ++ctl)
            br[ctl] = *(const bf16x8*)(W2F +
                (((size_t)(l*16 + 4*wc + ctl) * 32 + 4*ch + kt) * 64 + lane) * 8);
          bf16x8 a[2];
          #pragma unroll
          for (int rt = 0; rt < 2; ++rt)
            a[rt] = *(const bf16x8*)&sHc[rbase + 16*rt + li][32*kt + 8*lg];
          #pragma unroll
          for (int ctl = 0; ctl < 4; ++ctl)
            #pragma unroll
            for (int rt = 0; rt < 2; ++rt)
              fa[rt][ctl] = __builtin_amdgcn_mfma_f32_16x16x32_bf16(a[rt], br[ctl], fa[rt][ctl], 0, 0, 0);
        }
        if (ch < 7) mfma1(nxt);
      }

      // ---- residual + bias + LN2
      float g4[4], bb4[4], b2v[4];
      #pragma unroll
      for (int ctl = 0; ctl < 4; ++ctl){
        int col = 64*wc + 16*ctl + li;
        g4[ctl] = ln2s[l*256 + col]; bb4[ctl] = ln2b[l*256 + col]; b2v[ctl] = b2[l*256 + col];
      }
      float s1v[2][4], s2v[2][4];
      #pragma unroll
      for (int rt = 0; rt < 2; ++rt)
        #pragma unroll
        for (int r = 0; r < 4; ++r){
          float t1 = 0.f, t2 = 0.f;
          #pragma unroll
          for (int ctl = 0; ctl < 4; ++ctl){
            float y = fa[rt][ctl][r] + xres[rt][ctl][r] + b2v[ctl];
            fa[rt][ctl][r] = y; t1 += y; t2 += y * y;
          }
          #pragma unroll
          for (int o = 1; o < 16; o <<= 1){ t1 += __shfl_xor(t1, o, 64); t2 += __shfl_xor(t2, o, 64); }
          s1v[rt][r] = t1; s2v[rt][r] = t2;
        }
      if (li == 0){
        #pragma unroll
        for (int rt = 0; rt < 2; ++rt)
          #pragma unroll
          for (int r = 0; r < 4; ++r){
            sStat[rbase + 16*rt + 4*lg + r][wc] = s1v[rt][r];
            sStat[rbase + 16*rt + 4*lg + r][4 + wc] = s2v[rt][r];
          }
      }
      SBAR();
      #pragma unroll
      for (int rt = 0; rt < 2; ++rt)
        #pragma unroll
        for (int r = 0; r < 4; ++r){
          int row = rbase + 16*rt + 4*lg + r;
          float su = sStat[row][0] + sStat[row][1] + sStat[row][2] + sStat[row][3];
          float sq = sStat[row][4] + sStat[row][5] + sStat[row][6] + sStat[row][7];
          float mean = su * (1.f / 256.f);
          float var = sq * (1.f / 256.f) - mean * mean;
          float rs = rsqrtf(var + 1e-5f);
          #pragma unroll
          for (int ctl = 0; ctl < 4; ++ctl){
            int col = 64*wc + 16*ctl + li;
            float nv = (fa[rt][ctl][r] - mean) * rs * g4[ctl] + bb4[ctl];
            xres[rt][ctl][r] = nv;
            sXb[xoff(row, col)] = (u16)f2bf(nv);
            if (l == 3 && outCLS && row == 0) outCLS[term * 256 + col] = nv;
          }
        }
      SBAR();
    }
  }
}

extern "C" void kernel_launch(void* const* d_in, const int* in_sizes, int n_in,
                              void* d_out, int out_size, void* d_ws, size_t ws_size,
                              hipStream_t stream)
{
  (void)in_sizes; (void)n_in; (void)out_size; (void)ws_size;
  const int* tokens_scope = (const int*)d_in[0];
  const int* tokens_hole  = (const int*)d_in[1];
  const void* pad_scope = d_in[2];
  const void* pad_hole  = d_in[3];
  const void* ref_scope = d_in[4];
  const void* ref_hole  = d_in[5];
  const int* scope_sort = (const int*)d_in[6];
  const int* scope_pos  = (const int*)d_in[7];
  const float* emb  = (const float*)d_in[8];
  const float* Wq   = (const float*)d_in[9];
  const float* Wk   = (const float*)d_in[10];
  const float* Wv   = (const float*)d_in[11];
  const float* Wo   = (const float*)d_in[12];
  const float* ln1s = (const float*)d_in[13];
  const float* ln1b = (const float*)d_in[14];
  const float* W1   = (const float*)d_in[15];
  const float* b1   = (const float*)d_in[16];
  const float* W2   = (const float*)d_in[17];
  const float* b2   = (const float*)d_in[18];
  const float* ln2s = (const float*)d_in[19];
  const float* ln2b = (const float*)d_in[20];

  char* p = (char*)d_ws;
  float* reprs  = (float*)p; p += (size_t)2048*256*4;
  float* encCLS = (float*)p; p += (size_t)2048*256*4;
  u16* WqF = (u16*)p; p += (size_t)4*256*256*2;
  u16* WkF = (u16*)p; p += (size_t)4*256*256*2;
  u16* WvF = (u16*)p; p += (size_t)4*256*256*2;
  u16* WoF = (u16*)p; p += (size_t)4*256*256*2;
  u16* W1F = (u16*)p; p += (size_t)4*256*1024*2;
  u16* W2F = (u16*)p; p += (size_t)4*256*1024*2;
  u16* embB = (u16*)p; p += (size_t)3*2048*256*2;
  int* lists = (int*)p; p += (size_t)4*2048*4;
  int* counts = (int*)p; p += 64;
  int* flag = (int*)p; p += 16;

  hipLaunchKernelGGL(detect_bool_k, dim3(1), dim3(1), 0, stream, pad_scope, flag);
  hipLaunchKernelGGL(emb2bf_k, dim3(6144), dim3(256), 0, stream, emb, embB);
  hipLaunchKernelGGL(pack_k, dim3(1024), dim3(256), 0, stream, Wq, WqF, 256, 256);
  hipLaunchKernelGGL(pack_k, dim3(1024), dim3(256), 0, stream, Wk, WkF, 256, 256);
  hipLaunchKernelGGL(pack_k, dim3(1024), dim3(256), 0, stream, Wv, WvF, 256, 256);
  hipLaunchKernelGGL(pack_k, dim3(1024), dim3(256), 0, stream, Wo, WoF, 256, 256);
  hipLaunchKernelGGL(pack_k, dim3(4096), dim3(256), 0, stream, W1, W1F, 256, 1024);
  hipLaunchKernelGGL(pack_k, dim3(4096), dim3(256), 0, stream, W2, W2F, 1024, 256);
  hipLaunchKernelGGL(pos_init_k, dim3(2048), dim3(256), 0, stream, scope_pos, reprs);
  hipLaunchKernelGGL(zero_counts_k, dim3(1), dim3(64), 0, stream, counts);
  hipLaunchKernelGGL(compact_k, dim3(8), dim3(256), 0, stream, scope_sort, lists, counts);

  for (int r = 0; r < 4; ++r){
    hipLaunchKernelGGL(encode_k, dim3(2048), dim3(512), 0, stream,
      tokens_scope, pad_scope, ref_scope, flag, reprs, embB,
      WqF, WkF, WvF, WoF, W1F, b1, W2F, b2, ln1s, ln1b, ln2s, ln2b,
      lists + (size_t)r*2048, counts + r, encCLS);
    hipLaunchKernelGGL(update_k, dim3(2048), dim3(256), 0, stream, scope_sort, encCLS, reprs, r);
  }
  hipLaunchKernelGGL(encode_k, dim3(512), dim3(512), 0, stream,
      tokens_hole, pad_hole, ref_hole, flag, reprs, embB,
      WqF, WkF, WvF, WoF, W1F, b1, W2F, b2, ln1s, ln1b, ln2s, ln2b,
      (const int*)nullptr, (const int*)nullptr, (float*)d_out + (size_t)2048*256);
  hipLaunchKernelGGL(writeout_k, dim3(2048), dim3(256), 0, stream, reprs, (float*)d_out);
}